// Round 4
// baseline (227.073 us; speedup 1.0000x reference)
//
#include <hip/hip_runtime.h>
#include <hip/hip_bf16.h>

typedef __hip_bfloat16 bf16;
typedef __attribute__((ext_vector_type(8))) short bf16x8;
typedef __attribute__((ext_vector_type(4))) float f32x4;

#define MFMA_BF16(a, b, c) __builtin_amdgcn_mfma_f32_16x16x32_bf16((a), (b), (c), 0, 0, 0)

#define B_   2
#define S_   2048
#define HID_ 2048
#define H_   16
#define HKV_ 4
#define D_   128

#define GLOAD_LDS(gptr, lptr) \
  __builtin_amdgcn_global_load_lds((const __attribute__((address_space(1))) void*)(gptr), \
                                   (__attribute__((address_space(3))) void*)(lptr), 16, 0, 0)

// ---------------------------------------------------------------- fp32 -> bf16
__global__ void cvt_f32_bf16(const float* __restrict__ src, bf16* __restrict__ dst, int n) {
  int i = (blockIdx.x * 256 + threadIdx.x) * 4;
  if (i >= n) return;
  float4 v = *reinterpret_cast<const float4*>(src + i);
  alignas(8) bf16 t[4];
  t[0] = __float2bfloat16(v.x);
  t[1] = __float2bfloat16(v.y);
  t[2] = __float2bfloat16(v.z);
  t[3] = __float2bfloat16(v.w);
  *reinterpret_cast<short4*>(dst + i) = *reinterpret_cast<const short4*>(t);
}

// ---------------------------------------------------------------- per-position sequence start
__global__ void seq_start(const int* __restrict__ seq, int* __restrict__ sstart) {
  int t = blockIdx.x * 256 + threadIdx.x;  // 0..8191
  int b = t >> 11, s = t & (S_ - 1);
  const int* sb = seq + b * S_;
  int sid = sb[s];
  int lo = 0, hi = s;
  while (lo < hi) {
    int mid = (lo + hi) >> 1;
    if (sb[mid] < sid) lo = mid + 1; else hi = mid;
  }
  sstart[t] = lo;
}

// ---------------------------------------------------------------- GEMM: C[M][N] = A[M][K] * B[N][K]^T
// 128x128 tile, BK=64, 4 waves. 2-phase pipelined K-loop (T3-minimum):
// stage(t+1) issued BEFORE compute(t); one barrier (vmcnt drain) per tile.
// LDS double-buffered (64 KB). T5 setprio around MFMA; T1 bijective XCD swizzle.
template <int OUT_BF16>
__global__ __launch_bounds__(256) void gemm_bt(const bf16* __restrict__ A,
                                               const bf16* __restrict__ Bw,
                                               void* __restrict__ Cout,
                                               int M, int N, int K) {
  __shared__ bf16 As[2][128 * 64];
  __shared__ bf16 Bs[2][128 * 64];
  const int tid  = threadIdx.x;
  const int lane = tid & 63;
  const int w    = tid >> 6;
  const int wr   = w >> 1, wc = w & 1;
  const int ln15 = lane & 15, g = lane >> 4;

  // bijective XCD-aware remap (all our grids have nwg % 8 == 0)
  const int gx  = gridDim.x;
  const int nwg = gx * gridDim.y;
  int bid = blockIdx.y * gx + blockIdx.x;
  if ((nwg & 7) == 0) bid = (bid & 7) * (nwg >> 3) + (bid >> 3);
  const int n0 = (bid % gx) * 128;
  const int m0 = (bid / gx) * 128;

  f32x4 acc[4][4] = {};

  auto stage = [&](int buf, int kt) {
#pragma unroll
    for (int r = 0; r < 4; r++) {
      int idx = r * 256 + tid;
      int row = idx >> 3;
      int col = (idx & 7) << 3;
      int ldsbase = (r * 256 + w * 64) * 8;  // elements (wave-uniform)
      GLOAD_LDS(A + (size_t)(m0 + row) * K + kt + col, &As[buf][ldsbase]);
      GLOAD_LDS(Bw + (size_t)(n0 + row) * K + kt + col, &Bs[buf][ldsbase]);
    }
  };

  auto compute = [&](int buf) {
#pragma unroll
    for (int kk = 0; kk < 2; kk++) {
      bf16x8 af[4], bfr[4];
#pragma unroll
      for (int m = 0; m < 4; m++)
        af[m] = *reinterpret_cast<const bf16x8*>(&As[buf][(wr * 64 + m * 16 + ln15) * 64 + kk * 32 + g * 8]);
#pragma unroll
      for (int n = 0; n < 4; n++)
        bfr[n] = *reinterpret_cast<const bf16x8*>(&Bs[buf][(wc * 64 + n * 16 + ln15) * 64 + kk * 32 + g * 8]);
      __builtin_amdgcn_s_setprio(1);
#pragma unroll
      for (int m = 0; m < 4; m++)
#pragma unroll
        for (int n = 0; n < 4; n++)
          acc[m][n] = MFMA_BF16(af[m], bfr[n], acc[m][n]);
      __builtin_amdgcn_s_setprio(0);
    }
  };

  const int nt = K >> 6;
  stage(0, 0);
  __syncthreads();          // tile 0 staged (vmcnt drained at barrier)
  int buf = 0;
  for (int t = 0; t < nt - 1; ++t) {
    stage(buf ^ 1, (t + 1) << 6);  // issue next tile early (hides under compute)
    compute(buf);
    __syncthreads();               // drains vmcnt -> next tile ready; buf free
    buf ^= 1;
  }
  compute(buf);

  // epilogue: C row = m0 + wr*64 + m*16 + g*4 + r ; col = n0 + wc*64 + n*16 + ln15
#pragma unroll
  for (int m = 0; m < 4; m++)
#pragma unroll
    for (int n = 0; n < 4; n++)
#pragma unroll
      for (int r = 0; r < 4; r++) {
        int row = m0 + wr * 64 + m * 16 + g * 4 + r;
        int col = n0 + wc * 64 + n * 16 + ln15;
        if constexpr (OUT_BF16) {
          ((bf16*)Cout)[(size_t)row * N + col] = __float2bfloat16(acc[m][n][r]);
        } else {
          ((float*)Cout)[(size_t)row * N + col] = acc[m][n][r];
        }
      }
}

// ---------------------------------------------------------------- clip + RoPE + layout
__global__ __launch_bounds__(256) void qkv_post(const bf16* __restrict__ QKV,
                                                const int* __restrict__ wpos,
                                                bf16* __restrict__ Qs,   // [B][H][S][D]
                                                bf16* __restrict__ Ks,   // [B][HKV][S][D]
                                                bf16* __restrict__ Vt) { // [B][HKV][D][S]
  const int row = blockIdx.x;  // b*S + s
  const int b = row >> 11, s = row & (S_ - 1);
  const int t = threadIdx.x;
  const bf16* R = QKV + (size_t)row * 3072;
  const float pos = (float)wpos[row];
  const float kln = 0.14391156831212787f;   // ln(10000)/64
  const float qscale = 0.08838834764831845f; // 1/sqrt(128)

  for (int p = t; p < 1024; p += 256) {
    int h = p >> 6, i = p & 63;
    float ang = pos * expf(-(float)i * kln);
    float sn, cs;
    sincosf(ang, &sn, &cs);
    float x1 = __bfloat162float(R[h * 128 + i]);
    float x2 = __bfloat162float(R[h * 128 + 64 + i]);
    x1 = fminf(fmaxf(x1, -8.f), 8.f);
    x2 = fminf(fmaxf(x2, -8.f), 8.f);
    float y1 = (x1 * cs - x2 * sn) * qscale;
    float y2 = (x2 * cs + x1 * sn) * qscale;
    size_t qb = ((size_t)(b * H_ + h) * S_ + s) * D_;
    Qs[qb + i]      = __float2bfloat16(y1);
    Qs[qb + 64 + i] = __float2bfloat16(y2);
  }
  {
    int kh = t >> 6, i = t & 63;
    float ang = pos * expf(-(float)i * kln);
    float sn, cs;
    sincosf(ang, &sn, &cs);
    float x1 = __bfloat162float(R[2048 + kh * 128 + i]);
    float x2 = __bfloat162float(R[2048 + kh * 128 + 64 + i]);
    x1 = fminf(fmaxf(x1, -8.f), 8.f);
    x2 = fminf(fmaxf(x2, -8.f), 8.f);
    float y1 = x1 * cs - x2 * sn;
    float y2 = x2 * cs + x1 * sn;
    size_t kb = ((size_t)(b * HKV_ + kh) * S_ + s) * D_;
    Ks[kb + i]      = __float2bfloat16(y1);
    Ks[kb + 64 + i] = __float2bfloat16(y2);
  }
  for (int e = t; e < 512; e += 256) {
    int kh = e >> 7, d = e & 127;
    float x = __bfloat162float(R[2560 + e]);
    x = fminf(fmaxf(x, -8.f), 8.f);
    Vt[((size_t)(b * HKV_ + kh) * D_ + d) * S_ + s] = __float2bfloat16(x);
  }
}

// ---------------------------------------------------------------- flash attention
// Block = 4 waves = the 4 heads of one KV group, same (b, 16-query tile).
// K[32][128] + V^T[128][32] double-buffered in LDS via global_load_lds,
// XOR-swizzled (source-side pre-swizzle; linear LDS dest).
__global__ __launch_bounds__(256) void attn_fwd(const bf16* __restrict__ Qs,
                                                const bf16* __restrict__ Ks,
                                                const bf16* __restrict__ Vt,
                                                const int* __restrict__ sstart,
                                                bf16* __restrict__ att) {  // [B][S][H*D]
  __shared__ bf16 Kl[2][32 * 128];   // slot(16B) s=row*16+c holds K[row][(c^(row&15))*8..+7]
  __shared__ bf16 Vl[2][128 * 32];   // slot s=d*4+c holds Vt[d][kb+((c^(d&3))*8)..+7]
  __shared__ bf16 Plds[4][16 * 32];

  const int tid = threadIdx.x;
  const int lane = tid & 63, w = tid >> 6;
  const int ln15 = lane & 15, g = lane >> 4;

  const int wg = ((blockIdx.x & 7) << 7) | (blockIdx.x >> 3);
  const int qt  = wg & 127;
  const int kvh = (wg >> 7) & 3;
  const int b   = wg >> 9;
  const int h   = kvh * 4 + w;
  const int q0  = qt * 16;
  const int qi  = q0 + ln15;

  const bf16* Qrow = Qs + ((size_t)(b * H_ + h) * S_ + qi) * D_;
  bf16x8 qf[4];
#pragma unroll
  for (int c = 0; c < 4; c++)
    qf[c] = *reinterpret_cast<const bf16x8*>(Qrow + c * 32 + g * 8);

  const int sQ = sstart[b * S_ + qi];
  const int kstart = __builtin_amdgcn_readfirstlane(__shfl(sQ, 0));
  const int kend = q0 + 15;

  const bf16* Kb = Ks + (size_t)(b * HKV_ + kvh) * S_ * D_;
  const bf16* Vb = Vt + (size_t)(b * HKV_ + kvh) * D_ * S_;

  auto stage = [&](int buf, int kb) {
#pragma unroll
    for (int p = 0; p < 2; p++) {
      int slot = p * 256 + tid;
      int row = slot >> 4;
      int cs = (slot & 15) ^ (row & 15);
      int gr = min(kb + row, S_ - 1);
      GLOAD_LDS(Kb + (size_t)gr * D_ + cs * 8, &Kl[buf][(p * 256 + w * 64) * 8]);
    }
#pragma unroll
    for (int p = 0; p < 2; p++) {
      int slot = p * 256 + tid;
      int d = slot >> 2, c = slot & 3;
      int cs = c ^ (d & 3);
      int gcol = min(kb + cs * 8, S_ - 8);
      GLOAD_LDS(Vb + (size_t)d * S_ + gcol, &Vl[buf][(p * 256 + w * 64) * 8]);
    }
  };

  float m = -1e30f, lsum = 0.f;
  f32x4 o[8] = {};

  stage(0, kstart);
  int buf = 0;
  for (int kb = kstart; kb <= kend; kb += 32) {
    __syncthreads();
    if (kb + 32 <= kend) stage(buf ^ 1, kb + 32);

    bf16x8 kf0[4], kf1[4];
#pragma unroll
    for (int c = 0; c < 4; c++) {
      kf0[c] = *reinterpret_cast<const bf16x8*>(&Kl[buf][ln15 * 128 + (((c * 4 + g) ^ ln15) << 3)]);
      kf1[c] = *reinterpret_cast<const bf16x8*>(&Kl[buf][(16 + ln15) * 128 + (((c * 4 + g) ^ ln15) << 3)]);
    }
    f32x4 s0 = {0.f, 0.f, 0.f, 0.f}, s1 = {0.f, 0.f, 0.f, 0.f};
#pragma unroll
    for (int c = 0; c < 4; c++) {
      s0 = MFMA_BF16(kf0[c], qf[c], s0);
      s1 = MFMA_BF16(kf1[c], qf[c], s1);
    }

    float sc[8];
    float tmax = -1e30f;
#pragma unroll
    for (int r = 0; r < 4; r++) {
      int k0i = kb + g * 4 + r;
      int k1i = k0i + 16;
      float x0 = (k0i >= sQ && k0i <= qi) ? s0[r] : -1e30f;
      float x1 = (k1i >= sQ && k1i <= qi) ? s1[r] : -1e30f;
      sc[r] = x0;
      sc[4 + r] = x1;
      tmax = fmaxf(tmax, fmaxf(x0, x1));
    }
    tmax = fmaxf(tmax, __shfl_xor(tmax, 16));
    tmax = fmaxf(tmax, __shfl_xor(tmax, 32));
    float mn  = fmaxf(m, tmax);
    float fac = __expf(m - mn);
    float ps = 0.f;
    alignas(16) bf16 pb[8];
#pragma unroll
    for (int i2 = 0; i2 < 8; i2++) {
      float p = (sc[i2] < -1e29f) ? 0.f : __expf(sc[i2] - mn);
      ps += p;
      pb[i2] = __float2bfloat16(p);
    }
    ps += __shfl_xor(ps, 16);
    ps += __shfl_xor(ps, 32);
    lsum = lsum * fac + ps;
    m = mn;
#pragma unroll
    for (int t2 = 0; t2 < 8; t2++) o[t2] *= fac;

    *reinterpret_cast<short4*>(&Plds[w][ln15 * 32 + g * 4])      = *reinterpret_cast<const short4*>(&pb[0]);
    *reinterpret_cast<short4*>(&Plds[w][ln15 * 32 + 16 + g * 4]) = *reinterpret_cast<const short4*>(&pb[4]);
    __builtin_amdgcn_wave_barrier();
    bf16x8 pf = *reinterpret_cast<const bf16x8*>(&Plds[w][ln15 * 32 + g * 8]);

#pragma unroll
    for (int t2 = 0; t2 < 8; t2++) {
      int d = t2 * 16 + ln15;
      bf16x8 vf = *reinterpret_cast<const bf16x8*>(&Vl[buf][d * 32 + ((g ^ (ln15 & 3)) << 3)]);
      o[t2] = MFMA_BF16(vf, pf, o[t2]);
    }
    __builtin_amdgcn_wave_barrier();
    buf ^= 1;
  }

  float inv = 1.f / lsum;
#pragma unroll
  for (int t2 = 0; t2 < 8; t2++)
#pragma unroll
    for (int r = 0; r < 4; r++) {
      int d = t2 * 16 + g * 4 + r;
      att[((size_t)(b * S_ + qi)) * (H_ * D_) + h * D_ + d] = __float2bfloat16(o[t2][r] * inv);
    }
}

// ---------------------------------------------------------------- launcher
extern "C" void kernel_launch(void* const* d_in, const int* in_sizes, int n_in,
                              void* d_out, int out_size, void* d_ws, size_t ws_size,
                              hipStream_t stream) {
  const float* hidden = (const float*)d_in[0];
  const int* wpos = (const int*)d_in[1];
  const int* seq = (const int*)d_in[3];
  const float* Wq = (const float*)d_in[4];
  const float* Wk = (const float*)d_in[5];
  const float* Wv = (const float*)d_in[6];
  const float* Wo = (const float*)d_in[7];

  char* ws = (char*)d_ws;
  bf16* Xb   = (bf16*)(ws);
  bf16* Wqkv = (bf16*)(ws + 16777216);
  bf16* Wob  = (bf16*)(ws + 29360128);
  bf16* QKVb = (bf16*)(ws + 37748736);
  bf16* Ksb  = (bf16*)(ws + 62914560);
  bf16* Vtb  = (bf16*)(ws + 67108864);
  int*  sst  = (int*)(ws + 71303168);
  bf16* Qsb  = Xb;
  bf16* attb = QKVb;

  cvt_f32_bf16<<<dim3(8192), dim3(256), 0, stream>>>(hidden, Xb, 8388608);
  cvt_f32_bf16<<<dim3(4096), dim3(256), 0, stream>>>(Wq, Wqkv, 4194304);
  cvt_f32_bf16<<<dim3(1024), dim3(256), 0, stream>>>(Wk, Wqkv + 4194304, 1048576);
  cvt_f32_bf16<<<dim3(1024), dim3(256), 0, stream>>>(Wv, Wqkv + 5242880, 1048576);
  cvt_f32_bf16<<<dim3(4096), dim3(256), 0, stream>>>(Wo, Wob, 4194304);
  seq_start<<<dim3(32), dim3(256), 0, stream>>>(seq, sst);

  gemm_bt<1><<<dim3(24, 32), dim3(256), 0, stream>>>(Xb, Wqkv, (void*)QKVb, 4096, 3072, 2048);

  qkv_post<<<dim3(4096), dim3(256), 0, stream>>>(QKVb, wpos, Qsb, Ksb, Vtb);

  attn_fwd<<<dim3(1024), dim3(256), 0, stream>>>(Qsb, Ksb, Vtb, sst, attb);

  gemm_bt<0><<<dim3(16, 32), dim3(256), 0, stream>>>(attb, Wob, d_out, 4096, 2048, 2048);
}

// Round 5
// 219.643 us; speedup vs baseline: 1.0338x; 1.0338x over previous
//
#include <hip/hip_runtime.h>
#include <hip/hip_bf16.h>

typedef __hip_bfloat16 bf16;
typedef __attribute__((ext_vector_type(8))) short bf16x8;
typedef __attribute__((ext_vector_type(4))) float f32x4;

#define MFMA_BF16(a, b, c) __builtin_amdgcn_mfma_f32_16x16x32_bf16((a), (b), (c), 0, 0, 0)

#define B_   2
#define S_   2048
#define HID_ 2048
#define H_   16
#define HKV_ 4
#define D_   128

#define GLOAD_LDS(gptr, lptr) \
  __builtin_amdgcn_global_load_lds((const __attribute__((address_space(1))) void*)(gptr), \
                                   (__attribute__((address_space(3))) void*)(lptr), 16, 0, 0)

// counted-vmcnt barrier: loads stay in flight across the block barrier (T4)
template <int N>
__device__ __forceinline__ void vm_barrier() {
  __builtin_amdgcn_sched_barrier(0);
  if constexpr (N == 8)      asm volatile("s_waitcnt vmcnt(8)" ::: "memory");
  else if constexpr (N == 6) asm volatile("s_waitcnt vmcnt(6)" ::: "memory");
  else if constexpr (N == 4) asm volatile("s_waitcnt vmcnt(4)" ::: "memory");
  else if constexpr (N == 3) asm volatile("s_waitcnt vmcnt(3)" ::: "memory");
  else                       asm volatile("s_waitcnt vmcnt(0)" ::: "memory");
  __builtin_amdgcn_s_barrier();
  __builtin_amdgcn_sched_barrier(0);
}

// ---------------------------------------------------------------- fp32 -> bf16
__global__ void cvt_f32_bf16(const float* __restrict__ src, bf16* __restrict__ dst, int n) {
  int i = (blockIdx.x * 256 + threadIdx.x) * 4;
  if (i >= n) return;
  float4 v = *reinterpret_cast<const float4*>(src + i);
  alignas(8) bf16 t[4];
  t[0] = __float2bfloat16(v.x);
  t[1] = __float2bfloat16(v.y);
  t[2] = __float2bfloat16(v.z);
  t[3] = __float2bfloat16(v.w);
  *reinterpret_cast<short4*>(dst + i) = *reinterpret_cast<const short4*>(t);
}

// ---------------------------------------------------------------- per-position sequence start
__global__ void seq_start(const int* __restrict__ seq, int* __restrict__ sstart) {
  int t = blockIdx.x * 256 + threadIdx.x;  // 0..8191
  int b = t >> 11, s = t & (S_ - 1);
  const int* sb = seq + b * S_;
  int sid = sb[s];
  int lo = 0, hi = s;
  while (lo < hi) {
    int mid = (lo + hi) >> 1;
    if (sb[mid] < sid) lo = mid + 1; else hi = mid;
  }
  sstart[t] = lo;
}

// ---------------------------------------------------------------- pipelined GEMM
// C[M][N] = A[M][K] * B[N][K]^T.  BK=32, 8 waves (2Mx4N), per-wave (BM/2)x(BN/4).
// 4-deep LDS ring + counted vmcnt (tiles t+2,t+3 stay in flight across barriers).
// LDS swizzle: 16B-slot' = slot ^ ((row>>1)&3)  -> 2-way (free) on frag reads.
template <int BM, int BN, int OUT_BF16>
__global__ __launch_bounds__(512, 2) void gemm_pipe(const bf16* __restrict__ A,
                                                    const bf16* __restrict__ Bw,
                                                    void* __restrict__ Cout,
                                                    int M, int N, int K) {
  constexpr int MR = BM / 32;       // fragment repeats per wave (rows)
  constexpr int NR = BN / 64;       // fragment repeats per wave (cols)
  constexpr int LPTA = BM / 128;    // global_load_lds per thread per tile (A)
  constexpr int LPTB = BN / 128;
  constexpr int LPT = LPTA + LPTB;

  __shared__ bf16 As[4][BM * 32];
  __shared__ bf16 Bs[4][BN * 32];

  const int tid  = threadIdx.x;
  const int lane = tid & 63;
  const int w    = tid >> 6;
  const int wr   = w >> 2;          // 0..1
  const int wc   = w & 3;           // 0..3
  const int ln15 = lane & 15, g = lane >> 4;

  // bijective XCD-chunked remap (grids are multiples of 8)
  const int nwg = gridDim.x;
  int bid = blockIdx.x;
  bid = (bid & 7) * (nwg >> 3) + (bid >> 3);
  const int nbn = N / BN;
  const int m0 = (bid / nbn) * BM;
  const int n0 = (bid % nbn) * BN;

  f32x4 acc[MR][NR] = {};

  auto stage = [&](int buf, int kt) {
#pragma unroll
    for (int r = 0; r < LPTA; r++) {
      int sIdx = r * 512 + tid;
      int row = sIdx >> 2;
      int ss = (sIdx & 3) ^ ((row >> 1) & 3);
      GLOAD_LDS(A + (size_t)(m0 + row) * K + kt + ss * 8, &As[buf][(r * 512 + w * 64) * 8]);
    }
#pragma unroll
    for (int r = 0; r < LPTB; r++) {
      int sIdx = r * 512 + tid;
      int row = sIdx >> 2;
      int ss = (sIdx & 3) ^ ((row >> 1) & 3);
      GLOAD_LDS(Bw + (size_t)(n0 + row) * K + kt + ss * 8, &Bs[buf][(r * 512 + w * 64) * 8]);
    }
  };

  auto compute = [&](int buf) {
    bf16x8 af[MR], bf_[NR];
#pragma unroll
    for (int m = 0; m < MR; m++) {
      int row = wr * (BM / 2) + m * 16 + ln15;
      af[m] = *reinterpret_cast<const bf16x8*>(&As[buf][row * 32 + ((g ^ ((row >> 1) & 3)) << 3)]);
    }
#pragma unroll
    for (int n = 0; n < NR; n++) {
      int row = wc * (BN / 4) + n * 16 + ln15;
      bf_[n] = *reinterpret_cast<const bf16x8*>(&Bs[buf][row * 32 + ((g ^ ((row >> 1) & 3)) << 3)]);
    }
    __builtin_amdgcn_s_setprio(1);
#pragma unroll
    for (int m = 0; m < MR; m++)
#pragma unroll
      for (int n = 0; n < NR; n++)
        acc[m][n] = MFMA_BF16(af[m], bf_[n], acc[m][n]);
    __builtin_amdgcn_s_setprio(0);
  };

  const int NT = K >> 5;  // 64
  stage(0, 0);
  stage(1, 32);
  stage(2, 64);
  vm_barrier<2 * LPT>();   // tile 0 complete; tiles 1,2 in flight
  for (int t = 0; t < NT; ++t) {
    if (t + 3 < NT) stage((t + 3) & 3, (t + 3) << 5);
    compute(t & 3);
    if (t + 1 < NT) {
      if (t + 3 < NT)      vm_barrier<2 * LPT>();  // t+1 done; t+2,t+3 in flight
      else if (t + 2 < NT) vm_barrier<LPT>();
      else                 vm_barrier<0>();
    }
  }

  // epilogue: row = m0 + wr*(BM/2) + m*16 + g*4 + r ; col = n0 + wc*(BN/4) + n*16 + ln15
#pragma unroll
  for (int m = 0; m < MR; m++)
#pragma unroll
    for (int n = 0; n < NR; n++)
#pragma unroll
      for (int r = 0; r < 4; r++) {
        int row = m0 + wr * (BM / 2) + m * 16 + g * 4 + r;
        int col = n0 + wc * (BN / 4) + n * 16 + ln15;
        if constexpr (OUT_BF16) {
          ((bf16*)Cout)[(size_t)row * N + col] = __float2bfloat16(acc[m][n][r]);
        } else {
          ((float*)Cout)[(size_t)row * N + col] = acc[m][n][r];
        }
      }
}

// ---------------------------------------------------------------- clip + RoPE + layout
__global__ __launch_bounds__(256) void qkv_post(const bf16* __restrict__ QKV,
                                                const int* __restrict__ wpos,
                                                bf16* __restrict__ Qs,   // [B][H][S][D]
                                                bf16* __restrict__ Ks,   // [B][HKV][S][D]
                                                bf16* __restrict__ Vt) { // [B][HKV][D][S]
  const int row = blockIdx.x;  // b*S + s
  const int b = row >> 11, s = row & (S_ - 1);
  const int t = threadIdx.x;
  const bf16* R = QKV + (size_t)row * 3072;
  const float pos = (float)wpos[row];
  const float kln = 0.14391156831212787f;   // ln(10000)/64
  const float qscale = 0.08838834764831845f; // 1/sqrt(128)

  for (int p = t; p < 1024; p += 256) {
    int h = p >> 6, i = p & 63;
    float ang = pos * expf(-(float)i * kln);
    float sn, cs;
    sincosf(ang, &sn, &cs);
    float x1 = __bfloat162float(R[h * 128 + i]);
    float x2 = __bfloat162float(R[h * 128 + 64 + i]);
    x1 = fminf(fmaxf(x1, -8.f), 8.f);
    x2 = fminf(fmaxf(x2, -8.f), 8.f);
    float y1 = (x1 * cs - x2 * sn) * qscale;
    float y2 = (x2 * cs + x1 * sn) * qscale;
    size_t qb = ((size_t)(b * H_ + h) * S_ + s) * D_;
    Qs[qb + i]      = __float2bfloat16(y1);
    Qs[qb + 64 + i] = __float2bfloat16(y2);
  }
  {
    int kh = t >> 6, i = t & 63;
    float ang = pos * expf(-(float)i * kln);
    float sn, cs;
    sincosf(ang, &sn, &cs);
    float x1 = __bfloat162float(R[2048 + kh * 128 + i]);
    float x2 = __bfloat162float(R[2048 + kh * 128 + 64 + i]);
    x1 = fminf(fmaxf(x1, -8.f), 8.f);
    x2 = fminf(fmaxf(x2, -8.f), 8.f);
    float y1 = x1 * cs - x2 * sn;
    float y2 = x2 * cs + x1 * sn;
    size_t kb = ((size_t)(b * HKV_ + kh) * S_ + s) * D_;
    Ks[kb + i]      = __float2bfloat16(y1);
    Ks[kb + 64 + i] = __float2bfloat16(y2);
  }
  for (int e = t; e < 512; e += 256) {
    int kh = e >> 7, d = e & 127;
    float x = __bfloat162float(R[2560 + e]);
    x = fminf(fmaxf(x, -8.f), 8.f);
    Vt[((size_t)(b * HKV_ + kh) * D_ + d) * S_ + s] = __float2bfloat16(x);
  }
}

// ---------------------------------------------------------------- flash attention
// Block = 4 waves = the 4 heads of one KV group, same (b, 16-query tile).
__global__ __launch_bounds__(256) void attn_fwd(const bf16* __restrict__ Qs,
                                                const bf16* __restrict__ Ks,
                                                const bf16* __restrict__ Vt,
                                                const int* __restrict__ sstart,
                                                bf16* __restrict__ att) {  // [B][S][H*D]
  __shared__ bf16 Kl[2][32 * 128];
  __shared__ bf16 Vl[2][128 * 32];
  __shared__ bf16 Plds[4][16 * 32];

  const int tid = threadIdx.x;
  const int lane = tid & 63, w = tid >> 6;
  const int ln15 = lane & 15, g = lane >> 4;

  const int wg = ((blockIdx.x & 7) << 7) | (blockIdx.x >> 3);
  const int qt  = wg & 127;
  const int kvh = (wg >> 7) & 3;
  const int b   = wg >> 9;
  const int h   = kvh * 4 + w;
  const int q0  = qt * 16;
  const int qi  = q0 + ln15;

  const bf16* Qrow = Qs + ((size_t)(b * H_ + h) * S_ + qi) * D_;
  bf16x8 qf[4];
#pragma unroll
  for (int c = 0; c < 4; c++)
    qf[c] = *reinterpret_cast<const bf16x8*>(Qrow + c * 32 + g * 8);

  const int sQ = sstart[b * S_ + qi];
  const int kstart = __builtin_amdgcn_readfirstlane(__shfl(sQ, 0));
  const int kend = q0 + 15;

  const bf16* Kb = Ks + (size_t)(b * HKV_ + kvh) * S_ * D_;
  const bf16* Vb = Vt + (size_t)(b * HKV_ + kvh) * D_ * S_;

  auto stage = [&](int buf, int kb) {
#pragma unroll
    for (int p = 0; p < 2; p++) {
      int slot = p * 256 + tid;
      int row = slot >> 4;
      int cs = (slot & 15) ^ (row & 15);
      int gr = min(kb + row, S_ - 1);
      GLOAD_LDS(Kb + (size_t)gr * D_ + cs * 8, &Kl[buf][(p * 256 + w * 64) * 8]);
    }
#pragma unroll
    for (int p = 0; p < 2; p++) {
      int slot = p * 256 + tid;
      int d = slot >> 2, c = slot & 3;
      int cs = c ^ (d & 3);
      int gcol = min(kb + cs * 8, S_ - 8);
      GLOAD_LDS(Vb + (size_t)d * S_ + gcol, &Vl[buf][(p * 256 + w * 64) * 8]);
    }
  };

  float m = -1e30f, lsum = 0.f;
  f32x4 o[8] = {};

  stage(0, kstart);
  int buf = 0;
  for (int kb = kstart; kb <= kend; kb += 32) {
    __syncthreads();
    if (kb + 32 <= kend) stage(buf ^ 1, kb + 32);

    bf16x8 kf0[4], kf1[4];
#pragma unroll
    for (int c = 0; c < 4; c++) {
      kf0[c] = *reinterpret_cast<const bf16x8*>(&Kl[buf][ln15 * 128 + (((c * 4 + g) ^ ln15) << 3)]);
      kf1[c] = *reinterpret_cast<const bf16x8*>(&Kl[buf][(16 + ln15) * 128 + (((c * 4 + g) ^ ln15) << 3)]);
    }
    f32x4 s0 = {0.f, 0.f, 0.f, 0.f}, s1 = {0.f, 0.f, 0.f, 0.f};
#pragma unroll
    for (int c = 0; c < 4; c++) {
      s0 = MFMA_BF16(kf0[c], qf[c], s0);
      s1 = MFMA_BF16(kf1[c], qf[c], s1);
    }

    float sc[8];
    float tmax = -1e30f;
#pragma unroll
    for (int r = 0; r < 4; r++) {
      int k0i = kb + g * 4 + r;
      int k1i = k0i + 16;
      float x0 = (k0i >= sQ && k0i <= qi) ? s0[r] : -1e30f;
      float x1 = (k1i >= sQ && k1i <= qi) ? s1[r] : -1e30f;
      sc[r] = x0;
      sc[4 + r] = x1;
      tmax = fmaxf(tmax, fmaxf(x0, x1));
    }
    tmax = fmaxf(tmax, __shfl_xor(tmax, 16));
    tmax = fmaxf(tmax, __shfl_xor(tmax, 32));
    float mn  = fmaxf(m, tmax);
    float fac = __expf(m - mn);
    float ps = 0.f;
    alignas(16) bf16 pb[8];
#pragma unroll
    for (int i2 = 0; i2 < 8; i2++) {
      float p = (sc[i2] < -1e29f) ? 0.f : __expf(sc[i2] - mn);
      ps += p;
      pb[i2] = __float2bfloat16(p);
    }
    ps += __shfl_xor(ps, 16);
    ps += __shfl_xor(ps, 32);
    lsum = lsum * fac + ps;
    m = mn;
#pragma unroll
    for (int t2 = 0; t2 < 8; t2++) o[t2] *= fac;

    *reinterpret_cast<short4*>(&Plds[w][ln15 * 32 + g * 4])      = *reinterpret_cast<const short4*>(&pb[0]);
    *reinterpret_cast<short4*>(&Plds[w][ln15 * 32 + 16 + g * 4]) = *reinterpret_cast<const short4*>(&pb[4]);
    __builtin_amdgcn_wave_barrier();
    bf16x8 pf = *reinterpret_cast<const bf16x8*>(&Plds[w][ln15 * 32 + g * 8]);

#pragma unroll
    for (int t2 = 0; t2 < 8; t2++) {
      int d = t2 * 16 + ln15;
      bf16x8 vf = *reinterpret_cast<const bf16x8*>(&Vl[buf][d * 32 + ((g ^ (ln15 & 3)) << 3)]);
      o[t2] = MFMA_BF16(vf, pf, o[t2]);
    }
    __builtin_amdgcn_wave_barrier();
    buf ^= 1;
  }

  float inv = 1.f / lsum;
#pragma unroll
  for (int t2 = 0; t2 < 8; t2++)
#pragma unroll
    for (int r = 0; r < 4; r++) {
      int d = t2 * 16 + g * 4 + r;
      att[((size_t)(b * S_ + qi)) * (H_ * D_) + h * D_ + d] = __float2bfloat16(o[t2][r] * inv);
    }
}

// ---------------------------------------------------------------- launcher
extern "C" void kernel_launch(void* const* d_in, const int* in_sizes, int n_in,
                              void* d_out, int out_size, void* d_ws, size_t ws_size,
                              hipStream_t stream) {
  const float* hidden = (const float*)d_in[0];
  const int* wpos = (const int*)d_in[1];
  const int* seq = (const int*)d_in[3];
  const float* Wq = (const float*)d_in[4];
  const float* Wk = (const float*)d_in[5];
  const float* Wv = (const float*)d_in[6];
  const float* Wo = (const float*)d_in[7];

  char* ws = (char*)d_ws;
  bf16* Xb   = (bf16*)(ws);
  bf16* Wqkv = (bf16*)(ws + 16777216);
  bf16* Wob  = (bf16*)(ws + 29360128);
  bf16* QKVb = (bf16*)(ws + 37748736);
  bf16* Ksb  = (bf16*)(ws + 62914560);
  bf16* Vtb  = (bf16*)(ws + 67108864);
  int*  sst  = (int*)(ws + 71303168);
  bf16* Qsb  = Xb;
  bf16* attb = QKVb;

  cvt_f32_bf16<<<dim3(8192), dim3(256), 0, stream>>>(hidden, Xb, 8388608);
  cvt_f32_bf16<<<dim3(4096), dim3(256), 0, stream>>>(Wq, Wqkv, 4194304);
  cvt_f32_bf16<<<dim3(1024), dim3(256), 0, stream>>>(Wk, Wqkv + 4194304, 1048576);
  cvt_f32_bf16<<<dim3(1024), dim3(256), 0, stream>>>(Wv, Wqkv + 5242880, 1048576);
  cvt_f32_bf16<<<dim3(4096), dim3(256), 0, stream>>>(Wo, Wob, 4194304);
  seq_start<<<dim3(32), dim3(256), 0, stream>>>(seq, sst);

  // QKV projection: [4096,2048] x [3072,2048]^T -> bf16 [4096,3072]
  gemm_pipe<256, 256, 1><<<dim3(192), dim3(512), 0, stream>>>(Xb, Wqkv, (void*)QKVb, 4096, 3072, 2048);

  qkv_post<<<dim3(4096), dim3(256), 0, stream>>>(QKVb, wpos, Qsb, Ksb, Vtb);

  attn_fwd<<<dim3(1024), dim3(256), 0, stream>>>(Qsb, Ksb, Vtb, sst, attb);

  // O projection: [4096,2048] x [2048,2048]^T -> fp32 d_out
  gemm_pipe<128, 256, 0><<<dim3(256), dim3(512), 0, stream>>>(attb, Wob, d_out, 4096, 2048, 2048);
}

// Round 6
// 187.838 us; speedup vs baseline: 1.2089x; 1.1693x over previous
//
#include <hip/hip_runtime.h>
#include <hip/hip_bf16.h>

typedef __hip_bfloat16 bf16;
typedef __attribute__((ext_vector_type(8))) short bf16x8;
typedef __attribute__((ext_vector_type(4))) float f32x4;

#define MFMA_BF16(a, b, c) __builtin_amdgcn_mfma_f32_16x16x32_bf16((a), (b), (c), 0, 0, 0)

#define B_   2
#define S_   2048
#define HID_ 2048
#define H_   16
#define HKV_ 4
#define D_   128

#define GLOAD_LDS(gptr, lptr) \
  __builtin_amdgcn_global_load_lds((const __attribute__((address_space(1))) void*)(gptr), \
                                   (__attribute__((address_space(3))) void*)(lptr), 16, 0, 0)

template <int N>
__device__ __forceinline__ void vmw() {
  if constexpr (N == 0)      asm volatile("s_waitcnt vmcnt(0)" ::: "memory");
  else if constexpr (N == 3) asm volatile("s_waitcnt vmcnt(3)" ::: "memory");
  else                       asm volatile("s_waitcnt vmcnt(4)" ::: "memory");
}

__device__ __forceinline__ void blk_barrier() {
  __builtin_amdgcn_sched_barrier(0);
  __builtin_amdgcn_s_barrier();
  __builtin_amdgcn_sched_barrier(0);
}

// ---------------------------------------------------------------- fp32 -> bf16
__global__ void cvt_f32_bf16(const float* __restrict__ src, bf16* __restrict__ dst, int n) {
  int i = (blockIdx.x * 256 + threadIdx.x) * 4;
  if (i >= n) return;
  float4 v = *reinterpret_cast<const float4*>(src + i);
  alignas(8) bf16 t[4];
  t[0] = __float2bfloat16(v.x);
  t[1] = __float2bfloat16(v.y);
  t[2] = __float2bfloat16(v.z);
  t[3] = __float2bfloat16(v.w);
  *reinterpret_cast<short4*>(dst + i) = *reinterpret_cast<const short4*>(t);
}

// ---------------------------------------------------------------- per-position sequence start
__global__ void seq_start(const int* __restrict__ seq, int* __restrict__ sstart) {
  int t = blockIdx.x * 256 + threadIdx.x;  // 0..8191
  int b = t >> 11, s = t & (S_ - 1);
  const int* sb = seq + b * S_;
  int sid = sb[s];
  int lo = 0, hi = s;
  while (lo < hi) {
    int mid = (lo + hi) >> 1;
    if (sb[mid] < sid) lo = mid + 1; else hi = mid;
  }
  sstart[t] = lo;
}

// ---------------------------------------------------------------- 8-phase pipelined GEMM
// C[M][N] = A[M][K]*B[N][K]^T.  BK=64 as two k-halves (each = one MFMA K=32 step).
// 8 waves (2M x 4N), per-wave tile (BM/2) x 64.  2 LDS dbufs; per-phase:
// {ds_read frag subtile || stage 1 half-tile} -> s_barrier -> setprio MFMA -> s_barrier.
// Counted vmcnt (4 for BM=256 / 3 for BM=128) at checkpoint phases; vmcnt(0) only last 3 tiles.
// LDS swizzle: 16B-slot' = slot ^ ((row>>1)&3)  (2-way max = free; measured 0 conflicts).
template <int BM, int OUT_BF16>
__global__ __launch_bounds__(512, 2) void gemm8p(const bf16* __restrict__ A,
                                                 const bf16* __restrict__ Bw,
                                                 void* __restrict__ Cout,
                                                 int M, int N, int K) {
  constexpr int BN = 256;
  constexpr int MR = BM / 32;       // 8 (BM=256) or 4 (BM=128)
  constexpr int LA = BM / 128;      // A gload_lds per thread per half (2 or 1)
  constexpr int VCHK = (BM == 256) ? 4 : 3;

  __shared__ bf16 As[2][2][BM * 32];   // [dbuf][khalf][row*32+col]
  __shared__ bf16 Bs[2][2][BN * 32];

  const int tid  = threadIdx.x;
  const int lane = tid & 63;
  const int w    = tid >> 6;
  const int wr   = w >> 2;          // 0..1
  const int wc   = w & 3;           // 0..3
  const int ln15 = lane & 15, g = lane >> 4;

  // bijective XCD-chunked remap (grids are multiples of 8)
  const int nwg = gridDim.x;
  int bid = blockIdx.x;
  bid = (bid & 7) * (nwg >> 3) + (bid >> 3);
  const int nbn = N / BN;
  const int m0 = (bid / nbn) * BM;
  const int n0 = (bid % nbn) * BN;

  f32x4 acc[MR][4] = {};

  auto stageA = [&](int db, int kh, int t) {
    int kc = t * 64 + kh * 32;
#pragma unroll
    for (int r = 0; r < LA; r++) {
      int sIdx = r * 512 + tid;
      int row = sIdx >> 2;
      int ss = (sIdx & 3) ^ ((row >> 1) & 3);
      GLOAD_LDS(A + (size_t)(m0 + row) * K + kc + ss * 8, &As[db][kh][(r * 512 + w * 64) * 8]);
    }
  };
  auto stageB = [&](int db, int kh, int t) {
    int kc = t * 64 + kh * 32;
#pragma unroll
    for (int r = 0; r < 2; r++) {
      int sIdx = r * 512 + tid;
      int row = sIdx >> 2;
      int ss = (sIdx & 3) ^ ((row >> 1) & 3);
      GLOAD_LDS(Bw + (size_t)(n0 + row) * K + kc + ss * 8, &Bs[db][kh][(r * 512 + w * 64) * 8]);
    }
  };
  auto rdA = [&](bf16x8 (&af)[4], int db, int kh, int mb) {
#pragma unroll
    for (int m = 0; m < 4; m++) {
      int row = wr * (BM / 2) + (mb + m) * 16 + ln15;
      af[m] = *reinterpret_cast<const bf16x8*>(&As[db][kh][row * 32 + ((g ^ ((row >> 1) & 3)) << 3)]);
    }
  };
  auto rdB = [&](bf16x8 (&bfr)[4], int db, int kh) {
#pragma unroll
    for (int n = 0; n < 4; n++) {
      int row = wc * 64 + n * 16 + ln15;
      bfr[n] = *reinterpret_cast<const bf16x8*>(&Bs[db][kh][row * 32 + ((g ^ ((row >> 1) & 3)) << 3)]);
    }
  };

  bf16x8 af[4], bfr[4];
  auto MF = [&](int mb) {
    __builtin_amdgcn_s_setprio(1);
#pragma unroll
    for (int m = 0; m < 4; m++)
#pragma unroll
      for (int n = 0; n < 4; n++)
        acc[mb + m][n] = MFMA_BF16(af[m], bfr[n], acc[mb + m][n]);
    __builtin_amdgcn_s_setprio(0);
  };

  const int NT = K >> 6;  // 32

  // prologue: tile0 complete + tile1 kh0 in flight
  stageA(0, 0, 0); stageB(0, 0, 0);
  stageA(0, 1, 0); stageB(0, 1, 0);
  stageA(1, 0, 1); stageB(1, 0, 1);
  vmw<VCHK>();
  blk_barrier();

  for (int T = 0; T < NT; ++T) {
    const int db = T & 1, dn = db ^ 1;
    const bool tail = (T >= NT - 3);

    if constexpr (BM == 256) {
      // P1: kh0, m0-3 (+ B kh0)
      rdA(af, db, 0, 0); rdB(bfr, db, 0);
      if (T + 1 < NT) stageA(dn, 1, T + 1);
      blk_barrier(); MF(0); blk_barrier();
      // P2: kh0, m4-7
      rdA(af, db, 0, 4);
      if (T + 1 < NT) stageB(dn, 1, T + 1);
      if (tail) vmw<0>(); else vmw<4>();
      blk_barrier(); MF(4); blk_barrier();
      // P3: kh1, m0-3 (+ B kh1)
      rdA(af, db, 1, 0); rdB(bfr, db, 1);
      if (T + 2 < NT) stageA(db, 0, T + 2);
      blk_barrier(); MF(0); blk_barrier();
      // P4: kh1, m4-7
      rdA(af, db, 1, 4);
      if (T + 2 < NT) stageB(db, 0, T + 2);
      if (tail) vmw<0>(); else vmw<4>();
      blk_barrier(); MF(4); blk_barrier();
    } else {
      // P1: kh0 (all m)
      rdA(af, db, 0, 0); rdB(bfr, db, 0);
      if (T + 1 < NT) { stageA(dn, 1, T + 1); stageB(dn, 1, T + 1); }
      if (tail) vmw<0>(); else vmw<3>();
      blk_barrier(); MF(0); blk_barrier();
      // P2: kh1
      rdA(af, db, 1, 0); rdB(bfr, db, 1);
      if (T + 2 < NT) { stageA(db, 0, T + 2); stageB(db, 0, T + 2); }
      if (tail) vmw<0>(); else vmw<3>();
      blk_barrier(); MF(0); blk_barrier();
    }
  }

  // epilogue: row = m0 + wr*(BM/2) + m*16 + g*4 + r ; col = n0 + wc*64 + n*16 + ln15
#pragma unroll
  for (int m = 0; m < MR; m++)
#pragma unroll
    for (int n = 0; n < 4; n++)
#pragma unroll
      for (int r = 0; r < 4; r++) {
        int row = m0 + wr * (BM / 2) + m * 16 + g * 4 + r;
        int col = n0 + wc * 64 + n * 16 + ln15;
        if constexpr (OUT_BF16) {
          ((bf16*)Cout)[(size_t)row * N + col] = __float2bfloat16(acc[m][n][r]);
        } else {
          ((float*)Cout)[(size_t)row * N + col] = acc[m][n][r];
        }
      }
}

// ---------------------------------------------------------------- clip + RoPE + layout
__global__ __launch_bounds__(256) void qkv_post(const bf16* __restrict__ QKV,
                                                const int* __restrict__ wpos,
                                                bf16* __restrict__ Qs,   // [B][H][S][D]
                                                bf16* __restrict__ Ks,   // [B][HKV][S][D]
                                                bf16* __restrict__ Vt) { // [B][HKV][D][S]
  const int row = blockIdx.x;  // b*S + s
  const int b = row >> 11, s = row & (S_ - 1);
  const int t = threadIdx.x;
  const bf16* R = QKV + (size_t)row * 3072;
  const float pos = (float)wpos[row];
  const float kln = 0.14391156831212787f;   // ln(10000)/64
  const float qscale = 0.08838834764831845f; // 1/sqrt(128)

  for (int p = t; p < 1024; p += 256) {
    int h = p >> 6, i = p & 63;
    float ang = pos * expf(-(float)i * kln);
    float sn, cs;
    sincosf(ang, &sn, &cs);
    float x1 = __bfloat162float(R[h * 128 + i]);
    float x2 = __bfloat162float(R[h * 128 + 64 + i]);
    x1 = fminf(fmaxf(x1, -8.f), 8.f);
    x2 = fminf(fmaxf(x2, -8.f), 8.f);
    float y1 = (x1 * cs - x2 * sn) * qscale;
    float y2 = (x2 * cs + x1 * sn) * qscale;
    size_t qb = ((size_t)(b * H_ + h) * S_ + s) * D_;
    Qs[qb + i]      = __float2bfloat16(y1);
    Qs[qb + 64 + i] = __float2bfloat16(y2);
  }
  {
    int kh = t >> 6, i = t & 63;
    float ang = pos * expf(-(float)i * kln);
    float sn, cs;
    sincosf(ang, &sn, &cs);
    float x1 = __bfloat162float(R[2048 + kh * 128 + i]);
    float x2 = __bfloat162float(R[2048 + kh * 128 + 64 + i]);
    x1 = fminf(fmaxf(x1, -8.f), 8.f);
    x2 = fminf(fmaxf(x2, -8.f), 8.f);
    float y1 = x1 * cs - x2 * sn;
    float y2 = x2 * cs + x1 * sn;
    size_t kb = ((size_t)(b * HKV_ + kh) * S_ + s) * D_;
    Ks[kb + i]      = __float2bfloat16(y1);
    Ks[kb + 64 + i] = __float2bfloat16(y2);
  }
  for (int e = t; e < 512; e += 256) {
    int kh = e >> 7, d = e & 127;
    float x = __bfloat162float(R[2560 + e]);
    x = fminf(fmaxf(x, -8.f), 8.f);
    Vt[((size_t)(b * HKV_ + kh) * D_ + d) * S_ + s] = __float2bfloat16(x);
  }
}

// ---------------------------------------------------------------- flash attention
// Block = 4 waves = the 4 heads of one KV group, same (b, 16-query tile).
__global__ __launch_bounds__(256) void attn_fwd(const bf16* __restrict__ Qs,
                                                const bf16* __restrict__ Ks,
                                                const bf16* __restrict__ Vt,
                                                const int* __restrict__ sstart,
                                                bf16* __restrict__ att) {  // [B][S][H*D]
  __shared__ bf16 Kl[2][32 * 128];
  __shared__ bf16 Vl[2][128 * 32];
  __shared__ bf16 Plds[4][16 * 32];

  const int tid = threadIdx.x;
  const int lane = tid & 63, w = tid >> 6;
  const int ln15 = lane & 15, g = lane >> 4;

  const int wg = ((blockIdx.x & 7) << 7) | (blockIdx.x >> 3);
  const int qt  = wg & 127;
  const int kvh = (wg >> 7) & 3;
  const int b   = wg >> 9;
  const int h   = kvh * 4 + w;
  const int q0  = qt * 16;
  const int qi  = q0 + ln15;

  const bf16* Qrow = Qs + ((size_t)(b * H_ + h) * S_ + qi) * D_;
  bf16x8 qf[4];
#pragma unroll
  for (int c = 0; c < 4; c++)
    qf[c] = *reinterpret_cast<const bf16x8*>(Qrow + c * 32 + g * 8);

  const int sQ = sstart[b * S_ + qi];
  const int kstart = __builtin_amdgcn_readfirstlane(__shfl(sQ, 0));
  const int kend = q0 + 15;

  const bf16* Kb = Ks + (size_t)(b * HKV_ + kvh) * S_ * D_;
  const bf16* Vb = Vt + (size_t)(b * HKV_ + kvh) * D_ * S_;

  auto stage = [&](int buf, int kb) {
#pragma unroll
    for (int p = 0; p < 2; p++) {
      int slot = p * 256 + tid;
      int row = slot >> 4;
      int cs = (slot & 15) ^ (row & 15);
      int gr = min(kb + row, S_ - 1);
      GLOAD_LDS(Kb + (size_t)gr * D_ + cs * 8, &Kl[buf][(p * 256 + w * 64) * 8]);
    }
#pragma unroll
    for (int p = 0; p < 2; p++) {
      int slot = p * 256 + tid;
      int d = slot >> 2, c = slot & 3;
      int cs = c ^ (d & 3);
      int gcol = min(kb + cs * 8, S_ - 8);
      GLOAD_LDS(Vb + (size_t)d * S_ + gcol, &Vl[buf][(p * 256 + w * 64) * 8]);
    }
  };

  float m = -1e30f, lsum = 0.f;
  f32x4 o[8] = {};

  stage(0, kstart);
  int buf = 0;
  for (int kb = kstart; kb <= kend; kb += 32) {
    __syncthreads();
    if (kb + 32 <= kend) stage(buf ^ 1, kb + 32);

    bf16x8 kf0[4], kf1[4];
#pragma unroll
    for (int c = 0; c < 4; c++) {
      kf0[c] = *reinterpret_cast<const bf16x8*>(&Kl[buf][ln15 * 128 + (((c * 4 + g) ^ ln15) << 3)]);
      kf1[c] = *reinterpret_cast<const bf16x8*>(&Kl[buf][(16 + ln15) * 128 + (((c * 4 + g) ^ ln15) << 3)]);
    }
    f32x4 s0 = {0.f, 0.f, 0.f, 0.f}, s1 = {0.f, 0.f, 0.f, 0.f};
#pragma unroll
    for (int c = 0; c < 4; c++) {
      s0 = MFMA_BF16(kf0[c], qf[c], s0);
      s1 = MFMA_BF16(kf1[c], qf[c], s1);
    }

    float sc[8];
    float tmax = -1e30f;
#pragma unroll
    for (int r = 0; r < 4; r++) {
      int k0i = kb + g * 4 + r;
      int k1i = k0i + 16;
      float x0 = (k0i >= sQ && k0i <= qi) ? s0[r] : -1e30f;
      float x1 = (k1i >= sQ && k1i <= qi) ? s1[r] : -1e30f;
      sc[r] = x0;
      sc[4 + r] = x1;
      tmax = fmaxf(tmax, fmaxf(x0, x1));
    }
    tmax = fmaxf(tmax, __shfl_xor(tmax, 16));
    tmax = fmaxf(tmax, __shfl_xor(tmax, 32));
    float mn  = fmaxf(m, tmax);
    float fac = __expf(m - mn);
    float ps = 0.f;
    alignas(16) bf16 pb[8];
#pragma unroll
    for (int i2 = 0; i2 < 8; i2++) {
      float p = (sc[i2] < -1e29f) ? 0.f : __expf(sc[i2] - mn);
      ps += p;
      pb[i2] = __float2bfloat16(p);
    }
    ps += __shfl_xor(ps, 16);
    ps += __shfl_xor(ps, 32);
    lsum = lsum * fac + ps;
    m = mn;
#pragma unroll
    for (int t2 = 0; t2 < 8; t2++) o[t2] *= fac;

    *reinterpret_cast<short4*>(&Plds[w][ln15 * 32 + g * 4])      = *reinterpret_cast<const short4*>(&pb[0]);
    *reinterpret_cast<short4*>(&Plds[w][ln15 * 32 + 16 + g * 4]) = *reinterpret_cast<const short4*>(&pb[4]);
    __builtin_amdgcn_wave_barrier();
    bf16x8 pf = *reinterpret_cast<const bf16x8*>(&Plds[w][ln15 * 32 + g * 8]);

#pragma unroll
    for (int t2 = 0; t2 < 8; t2++) {
      int d = t2 * 16 + ln15;
      bf16x8 vf = *reinterpret_cast<const bf16x8*>(&Vl[buf][d * 32 + ((g ^ (ln15 & 3)) << 3)]);
      o[t2] = MFMA_BF16(vf, pf, o[t2]);
    }
    __builtin_amdgcn_wave_barrier();
    buf ^= 1;
  }

  float inv = 1.f / lsum;
#pragma unroll
  for (int t2 = 0; t2 < 8; t2++)
#pragma unroll
    for (int r = 0; r < 4; r++) {
      int d = t2 * 16 + g * 4 + r;
      att[((size_t)(b * S_ + qi)) * (H_ * D_) + h * D_ + d] = __float2bfloat16(o[t2][r] * inv);
    }
}

// ---------------------------------------------------------------- launcher
extern "C" void kernel_launch(void* const* d_in, const int* in_sizes, int n_in,
                              void* d_out, int out_size, void* d_ws, size_t ws_size,
                              hipStream_t stream) {
  const float* hidden = (const float*)d_in[0];
  const int* wpos = (const int*)d_in[1];
  const int* seq = (const int*)d_in[3];
  const float* Wq = (const float*)d_in[4];
  const float* Wk = (const float*)d_in[5];
  const float* Wv = (const float*)d_in[6];
  const float* Wo = (const float*)d_in[7];

  char* ws = (char*)d_ws;
  bf16* Xb   = (bf16*)(ws);
  bf16* Wqkv = (bf16*)(ws + 16777216);
  bf16* Wob  = (bf16*)(ws + 29360128);
  bf16* QKVb = (bf16*)(ws + 37748736);
  bf16* Ksb  = (bf16*)(ws + 62914560);
  bf16* Vtb  = (bf16*)(ws + 67108864);
  int*  sst  = (int*)(ws + 71303168);
  bf16* Qsb  = Xb;
  bf16* attb = QKVb;

  cvt_f32_bf16<<<dim3(8192), dim3(256), 0, stream>>>(hidden, Xb, 8388608);
  cvt_f32_bf16<<<dim3(4096), dim3(256), 0, stream>>>(Wq, Wqkv, 4194304);
  cvt_f32_bf16<<<dim3(1024), dim3(256), 0, stream>>>(Wk, Wqkv + 4194304, 1048576);
  cvt_f32_bf16<<<dim3(1024), dim3(256), 0, stream>>>(Wv, Wqkv + 5242880, 1048576);
  cvt_f32_bf16<<<dim3(4096), dim3(256), 0, stream>>>(Wo, Wob, 4194304);
  seq_start<<<dim3(32), dim3(256), 0, stream>>>(seq, sst);

  // QKV projection: [4096,2048] x [3072,2048]^T -> bf16 [4096,3072]
  gemm8p<256, 1><<<dim3(192), dim3(512), 0, stream>>>(Xb, Wqkv, (void*)QKVb, 4096, 3072, 2048);

  qkv_post<<<dim3(4096), dim3(256), 0, stream>>>(QKVb, wpos, Qsb, Ksb, Vtb);

  attn_fwd<<<dim3(1024), dim3(256), 0, stream>>>(Qsb, Ksb, Vtb, sst, attb);

  // O projection: [4096,2048] x [2048,2048]^T -> fp32 d_out
  gemm8p<128, 0><<<dim3(256), dim3(512), 0, stream>>>(attb, Wob, d_out, 4096, 2048, 2048);
}

// Round 7
// 179.249 us; speedup vs baseline: 1.2668x; 1.0479x over previous
//
#include <hip/hip_runtime.h>
#include <hip/hip_bf16.h>

typedef __hip_bfloat16 bf16;
typedef __attribute__((ext_vector_type(8))) short bf16x8;
typedef __attribute__((ext_vector_type(4))) float f32x4;

#define MFMA_BF16(a, b, c) __builtin_amdgcn_mfma_f32_16x16x32_bf16((a), (b), (c), 0, 0, 0)

#define B_   2
#define S_   2048
#define HID_ 2048
#define H_   16
#define HKV_ 4
#define D_   128

#define GLOAD_LDS(gptr, lptr) \
  __builtin_amdgcn_global_load_lds((const __attribute__((address_space(1))) void*)(gptr), \
                                   (__attribute__((address_space(3))) void*)(lptr), 16, 0, 0)

template <int N>
__device__ __forceinline__ void vmw() {
  if constexpr (N == 0)      asm volatile("s_waitcnt vmcnt(0)" ::: "memory");
  else if constexpr (N == 2) asm volatile("s_waitcnt vmcnt(2)" ::: "memory");
  else if constexpr (N == 3) asm volatile("s_waitcnt vmcnt(3)" ::: "memory");
  else if constexpr (N == 4) asm volatile("s_waitcnt vmcnt(4)" ::: "memory");
  else if constexpr (N == 5) asm volatile("s_waitcnt vmcnt(5)" ::: "memory");
  else                       asm volatile("s_waitcnt vmcnt(6)" ::: "memory");
}

__device__ __forceinline__ void blk_barrier() {
  __builtin_amdgcn_sched_barrier(0);
  __builtin_amdgcn_s_barrier();
  __builtin_amdgcn_sched_barrier(0);
}

// ---------------------------------------------------------------- fp32 -> bf16 (hidden)
__global__ void cvt_f32_bf16(const float* __restrict__ src, bf16* __restrict__ dst, int n) {
  int i = (blockIdx.x * 256 + threadIdx.x) * 4;
  if (i >= n) return;
  float4 v = *reinterpret_cast<const float4*>(src + i);
  alignas(8) bf16 t[4];
  t[0] = __float2bfloat16(v.x);
  t[1] = __float2bfloat16(v.y);
  t[2] = __float2bfloat16(v.z);
  t[3] = __float2bfloat16(v.w);
  *reinterpret_cast<short4*>(dst + i) = *reinterpret_cast<const short4*>(t);
}

// ---------------------------------------------------------------- all 4 weights in one launch
__global__ void cvt_weights(const float* __restrict__ Wq, const float* __restrict__ Wk,
                            const float* __restrict__ Wv, const float* __restrict__ Wo,
                            bf16* __restrict__ Wqkv, bf16* __restrict__ Wob) {
  int i = (blockIdx.x * 256 + threadIdx.x) * 4;  // virtual concat index
  const float* src; bf16* dst; int off;
  if (i < 4194304)      { src = Wq; dst = Wqkv;           off = i; }
  else if (i < 5242880) { src = Wk; dst = Wqkv + 4194304; off = i - 4194304; }
  else if (i < 6291456) { src = Wv; dst = Wqkv + 5242880; off = i - 5242880; }
  else                  { src = Wo; dst = Wob;            off = i - 6291456; }
  float4 v = *reinterpret_cast<const float4*>(src + off);
  alignas(8) bf16 t[4];
  t[0] = __float2bfloat16(v.x);
  t[1] = __float2bfloat16(v.y);
  t[2] = __float2bfloat16(v.z);
  t[3] = __float2bfloat16(v.w);
  *reinterpret_cast<short4*>(dst + off) = *reinterpret_cast<const short4*>(t);
}

// ---------------------------------------------------------------- per-position sequence start
__global__ void seq_start(const int* __restrict__ seq, int* __restrict__ sstart) {
  int t = blockIdx.x * 256 + threadIdx.x;  // 0..8191
  int b = t >> 11, s = t & (S_ - 1);
  const int* sb = seq + b * S_;
  int sid = sb[s];
  int lo = 0, hi = s;
  while (lo < hi) {
    int mid = (lo + hi) >> 1;
    if (sb[mid] < sid) lo = mid + 1; else hi = mid;
  }
  sstart[t] = lo;
}

// ---------------------------------------------------------------- 4-phase pipelined GEMM
// C[M][N] = A[M][K]*B[N][K]^T.  BK=64 (two k-halves), 8 waves (2M x 4N),
// per-wave (BM/2) x (BN/4).  2 LDS dbufs.
// Per tile T (4 phases): each = {ds_read frags || stage} -> bar -> setprio MFMA -> bar.
// Stage schedule (steady state, per-thread load queue in issue order):
//   P1: A-kh1(T+1)[LA]   P2: B-part(T+1)   P3: A-kh0(T+2)[LA]   P4: B-part
// BN=192: B(T+1) = 3 one-load passes: r0,r1 @P2 (covers kh0), r2 @P4 (rest of kh1).
//   checkpoints: P2: vmcnt(4)  [requires A-kh1(T),Br2(T); after them: A1(T+1)2+Br01(T+1)2]
//                P4: vmcnt(3)  [requires Br01(T+1),A-kh0(T+1); after: A0(T+2)2+Br2(T+1)1]
// BN=128: B staged per-half (1 load): B-kh1(T+1)@P2, B-kh0(T+2)@P4.
//   checkpoints: both vmcnt(6) [6 loads younger than the required set in both cases]
// Tail: T >= NT-2 -> stages skip -> counted values no longer bound the required
// loads -> use vmcnt(0).
// LDS swizzle: 16B-slot' = slot ^ ((row>>1)&3) (2-way max = free; 0 conflicts measured).
template <int BM, int BN, int OUT_BF16>
__global__ __launch_bounds__(512, 2) void gemm8p(const bf16* __restrict__ A,
                                                 const bf16* __restrict__ Bw,
                                                 void* __restrict__ Cout,
                                                 int M, int N, int K) {
  constexpr int MR = BM / 32;       // 8
  constexpr int NR = BN / 64;       // 3 (BN=192) or 2 (BN=128)
  constexpr int LA = BM / 128;      // 2

  __shared__ bf16 As[2][2][BM * 32];   // [dbuf][khalf]
  __shared__ bf16 Bs[2][2][BN * 32];

  const int tid  = threadIdx.x;
  const int lane = tid & 63;
  const int w    = tid >> 6;
  const int wr   = w >> 2;          // 0..1
  const int wc   = w & 3;           // 0..3
  const int ln15 = lane & 15, g = lane >> 4;

  // bijective XCD-chunked remap (grids are multiples of 8)
  const int nwg = gridDim.x;
  int bid = blockIdx.x;
  bid = (bid & 7) * (nwg >> 3) + (bid >> 3);
  const int nbn = N / BN;
  const int m0 = (bid / nbn) * BM;
  const int n0 = (bid % nbn) * BN;

  f32x4 acc[MR][NR] = {};

  auto stageA = [&](int db, int kh, int t) {
    int kc = t * 64 + kh * 32;
#pragma unroll
    for (int r = 0; r < LA; r++) {
      int sIdx = r * 512 + tid;
      int row = sIdx >> 2;
      int ss = (sIdx & 3) ^ ((row >> 1) & 3);
      GLOAD_LDS(A + (size_t)(m0 + row) * K + kc + ss * 8, &As[db][kh][(r * 512 + w * 64) * 8]);
    }
  };
  // BN=192: one pass r over the flat [2][BN][32] region (rows 0..2BN-1)
  auto stageB_r = [&](int db, int t, int r) {
    int slot = r * 512 + tid;
    int frow = slot >> 2;                 // 0..2BN-1
    int kh = frow >= BN;
    int brow = frow - kh * BN;
    int ss = (slot & 3) ^ ((brow >> 1) & 3);
    GLOAD_LDS(Bw + (size_t)(n0 + brow) * K + t * 64 + kh * 32 + ss * 8,
              &Bs[db][0][0] + (size_t)(r * 512 + w * 64) * 8);
  };
  // BN=128: one half in one pass
  auto stageB_h = [&](int db, int kh, int t) {
    int brow = tid >> 2;                  // 0..127
    int ss = (tid & 3) ^ ((brow >> 1) & 3);
    GLOAD_LDS(Bw + (size_t)(n0 + brow) * K + t * 64 + kh * 32 + ss * 8,
              &Bs[db][kh][(w * 64) * 8]);
  };

  bf16x8 af[4], bfr[NR];
  auto rdA = [&](int db, int kh, int mb) {
#pragma unroll
    for (int m = 0; m < 4; m++) {
      int row = wr * (BM / 2) + (mb + m) * 16 + ln15;
      af[m] = *reinterpret_cast<const bf16x8*>(&As[db][kh][row * 32 + ((g ^ ((row >> 1) & 3)) << 3)]);
    }
  };
  auto rdB = [&](int db, int kh) {
#pragma unroll
    for (int n = 0; n < NR; n++) {
      int row = wc * (BN / 4) + n * 16 + ln15;
      bfr[n] = *reinterpret_cast<const bf16x8*>(&Bs[db][kh][row * 32 + ((g ^ ((row >> 1) & 3)) << 3)]);
    }
  };
  auto MF = [&](int mb) {
    __builtin_amdgcn_s_setprio(1);
#pragma unroll
    for (int m = 0; m < 4; m++)
#pragma unroll
      for (int n = 0; n < NR; n++)
        acc[mb + m][n] = MFMA_BF16(af[m], bfr[n], acc[mb + m][n]);
    __builtin_amdgcn_s_setprio(0);
  };

  const int NT = K >> 6;  // 32

  // prologue (mimics the steady-state issue order of tiles -2/-1)
  if constexpr (BN == 192) {
    stageA(0, 0, 0);                         // A0(0) [2]
    stageB_r(0, 0, 0); stageB_r(0, 0, 1);    // Br01(0) [2]
    stageA(0, 1, 0);                         // A1(0) [2]
    stageB_r(0, 0, 2);                       // Br2(0) [1]
    stageA(1, 0, 1);                         // A0(1) [2]
    vmw<5>();                                // A0(0)+Br01(0) done; 5 in flight
  } else {
    stageA(0, 0, 0);                         // [2]
    stageB_h(0, 0, 0);                       // [1]
    stageA(0, 1, 0);                         // [2]
    stageB_h(0, 1, 0);                       // [1]
    stageA(1, 0, 1);                         // [2]
    stageB_h(1, 0, 1);                       // [1]
    vmw<6>();                                // A0(0)+B0(0) done; 6 in flight
  }
  blk_barrier();

  for (int T = 0; T < NT; ++T) {
    const int db = T & 1, dn = db ^ 1;
    const bool tail = (T >= NT - 2);

    // P1: kh0, m0-3
    rdA(db, 0, 0); rdB(db, 0);
    if (T + 1 < NT) stageA(dn, 1, T + 1);
    blk_barrier(); MF(0); blk_barrier();
    // P2: kh0, m4-7
    rdA(db, 0, 4);
    if constexpr (BN == 192) {
      if (T + 1 < NT) { stageB_r(dn, T + 1, 0); stageB_r(dn, T + 1, 1); }
      if (tail) vmw<0>(); else vmw<4>();
    } else {
      if (T + 1 < NT) stageB_h(dn, 1, T + 1);
      if (tail) vmw<0>(); else vmw<6>();
    }
    blk_barrier(); MF(4); blk_barrier();
    // P3: kh1, m0-3
    rdA(db, 1, 0); rdB(db, 1);
    if (T + 2 < NT) stageA(db, 0, T + 2);
    blk_barrier(); MF(0); blk_barrier();
    // P4: kh1, m4-7
    rdA(db, 1, 4);
    if constexpr (BN == 192) {
      if (T + 1 < NT) stageB_r(dn, T + 1, 2);
      if (tail) vmw<0>(); else vmw<3>();
    } else {
      if (T + 2 < NT) stageB_h(db, 0, T + 2);
      if (tail) vmw<0>(); else vmw<6>();
    }
    blk_barrier(); MF(4); blk_barrier();
  }

  // epilogue: row = m0 + wr*(BM/2) + m*16 + g*4 + r ; col = n0 + wc*(BN/4) + n*16 + ln15
#pragma unroll
  for (int m = 0; m < MR; m++)
#pragma unroll
    for (int n = 0; n < NR; n++)
#pragma unroll
      for (int r = 0; r < 4; r++) {
        int row = m0 + wr * (BM / 2) + m * 16 + g * 4 + r;
        int col = n0 + wc * (BN / 4) + n * 16 + ln15;
        if constexpr (OUT_BF16) {
          ((bf16*)Cout)[(size_t)row * N + col] = __float2bfloat16(acc[m][n][r]);
        } else {
          ((float*)Cout)[(size_t)row * N + col] = acc[m][n][r];
        }
      }
}

// ---------------------------------------------------------------- clip + RoPE + layout
__global__ __launch_bounds__(256) void qkv_post(const bf16* __restrict__ QKV,
                                                const int* __restrict__ wpos,
                                                bf16* __restrict__ Qs,   // [B][H][S][D]
                                                bf16* __restrict__ Ks,   // [B][HKV][S][D]
                                                bf16* __restrict__ Vt) { // [B][HKV][D][S]
  const int row = blockIdx.x;  // b*S + s
  const int b = row >> 11, s = row & (S_ - 1);
  const int t = threadIdx.x;
  const bf16* R = QKV + (size_t)row * 3072;
  const float pos = (float)wpos[row];
  const float kln = 0.14391156831212787f;   // ln(10000)/64
  const float qscale = 0.08838834764831845f; // 1/sqrt(128)

  for (int p = t; p < 1024; p += 256) {
    int h = p >> 6, i = p & 63;
    float ang = pos * expf(-(float)i * kln);
    float sn, cs;
    sincosf(ang, &sn, &cs);
    float x1 = __bfloat162float(R[h * 128 + i]);
    float x2 = __bfloat162float(R[h * 128 + 64 + i]);
    x1 = fminf(fmaxf(x1, -8.f), 8.f);
    x2 = fminf(fmaxf(x2, -8.f), 8.f);
    float y1 = (x1 * cs - x2 * sn) * qscale;
    float y2 = (x2 * cs + x1 * sn) * qscale;
    size_t qb = ((size_t)(b * H_ + h) * S_ + s) * D_;
    Qs[qb + i]      = __float2bfloat16(y1);
    Qs[qb + 64 + i] = __float2bfloat16(y2);
  }
  {
    int kh = t >> 6, i = t & 63;
    float ang = pos * expf(-(float)i * kln);
    float sn, cs;
    sincosf(ang, &sn, &cs);
    float x1 = __bfloat162float(R[2048 + kh * 128 + i]);
    float x2 = __bfloat162float(R[2048 + kh * 128 + 64 + i]);
    x1 = fminf(fmaxf(x1, -8.f), 8.f);
    x2 = fminf(fmaxf(x2, -8.f), 8.f);
    float y1 = x1 * cs - x2 * sn;
    float y2 = x2 * cs + x1 * sn;
    size_t kb = ((size_t)(b * HKV_ + kh) * S_ + s) * D_;
    Ks[kb + i]      = __float2bfloat16(y1);
    Ks[kb + 64 + i] = __float2bfloat16(y2);
  }
  for (int e = t; e < 512; e += 256) {
    int kh = e >> 7, d = e & 127;
    float x = __bfloat162float(R[2560 + e]);
    x = fminf(fmaxf(x, -8.f), 8.f);
    Vt[((size_t)(b * HKV_ + kh) * D_ + d) * S_ + s] = __float2bfloat16(x);
  }
}

// ---------------------------------------------------------------- flash attention
// Block = 4 waves = the 4 heads of one KV group, same (b, 16-query tile).
__global__ __launch_bounds__(256) void attn_fwd(const bf16* __restrict__ Qs,
                                                const bf16* __restrict__ Ks,
                                                const bf16* __restrict__ Vt,
                                                const int* __restrict__ sstart,
                                                bf16* __restrict__ att) {  // [B][S][H*D]
  __shared__ bf16 Kl[2][32 * 128];
  __shared__ bf16 Vl[2][128 * 32];
  __shared__ bf16 Plds[4][16 * 32];

  const int tid = threadIdx.x;
  const int lane = tid & 63, w = tid >> 6;
  const int ln15 = lane & 15, g = lane >> 4;

  const int wg = ((blockIdx.x & 7) << 7) | (blockIdx.x >> 3);
  const int qt  = wg & 127;
  const int kvh = (wg >> 7) & 3;
  const int b   = wg >> 9;
  const int h   = kvh * 4 + w;
  const int q0  = qt * 16;
  const int qi  = q0 + ln15;

  const bf16* Qrow = Qs + ((size_t)(b * H_ + h) * S_ + qi) * D_;
  bf16x8 qf[4];
#pragma unroll
  for (int c = 0; c < 4; c++)
    qf[c] = *reinterpret_cast<const bf16x8*>(Qrow + c * 32 + g * 8);

  const int sQ = sstart[b * S_ + qi];
  const int kstart = __builtin_amdgcn_readfirstlane(__shfl(sQ, 0));
  const int kend = q0 + 15;

  const bf16* Kb = Ks + (size_t)(b * HKV_ + kvh) * S_ * D_;
  const bf16* Vb = Vt + (size_t)(b * HKV_ + kvh) * D_ * S_;

  auto stage = [&](int buf, int kb) {
#pragma unroll
    for (int p = 0; p < 2; p++) {
      int slot = p * 256 + tid;
      int row = slot >> 4;
      int cs = (slot & 15) ^ (row & 15);
      int gr = min(kb + row, S_ - 1);
      GLOAD_LDS(Kb + (size_t)gr * D_ + cs * 8, &Kl[buf][(p * 256 + w * 64) * 8]);
    }
#pragma unroll
    for (int p = 0; p < 2; p++) {
      int slot = p * 256 + tid;
      int d = slot >> 2, c = slot & 3;
      int cs = c ^ (d & 3);
      int gcol = min(kb + cs * 8, S_ - 8);
      GLOAD_LDS(Vb + (size_t)d * S_ + gcol, &Vl[buf][(p * 256 + w * 64) * 8]);
    }
  };

  float m = -1e30f, lsum = 0.f;
  f32x4 o[8] = {};

  stage(0, kstart);
  int buf = 0;
  for (int kb = kstart; kb <= kend; kb += 32) {
    __syncthreads();
    if (kb + 32 <= kend) stage(buf ^ 1, kb + 32);

    bf16x8 kf0[4], kf1[4];
#pragma unroll
    for (int c = 0; c < 4; c++) {
      kf0[c] = *reinterpret_cast<const bf16x8*>(&Kl[buf][ln15 * 128 + (((c * 4 + g) ^ ln15) << 3)]);
      kf1[c] = *reinterpret_cast<const bf16x8*>(&Kl[buf][(16 + ln15) * 128 + (((c * 4 + g) ^ ln15) << 3)]);
    }
    f32x4 s0 = {0.f, 0.f, 0.f, 0.f}, s1 = {0.f, 0.f, 0.f, 0.f};
#pragma unroll
    for (int c = 0; c < 4; c++) {
      s0 = MFMA_BF16(kf0[c], qf[c], s0);
      s1 = MFMA_BF16(kf1[c], qf[c], s1);
    }

    float sc[8];
    float tmax = -1e30f;
#pragma unroll
    for (int r = 0; r < 4; r++) {
      int k0i = kb + g * 4 + r;
      int k1i = k0i + 16;
      float x0 = (k0i >= sQ && k0i <= qi) ? s0[r] : -1e30f;
      float x1 = (k1i >= sQ && k1i <= qi) ? s1[r] : -1e30f;
      sc[r] = x0;
      sc[4 + r] = x1;
      tmax = fmaxf(tmax, fmaxf(x0, x1));
    }
    tmax = fmaxf(tmax, __shfl_xor(tmax, 16));
    tmax = fmaxf(tmax, __shfl_xor(tmax, 32));
    float mn  = fmaxf(m, tmax);
    float fac = __expf(m - mn);
    float ps = 0.f;
    alignas(16) bf16 pb[8];
#pragma unroll
    for (int i2 = 0; i2 < 8; i2++) {
      float p = (sc[i2] < -1e29f) ? 0.f : __expf(sc[i2] - mn);
      ps += p;
      pb[i2] = __float2bfloat16(p);
    }
    ps += __shfl_xor(ps, 16);
    ps += __shfl_xor(ps, 32);
    lsum = lsum * fac + ps;
    m = mn;
#pragma unroll
    for (int t2 = 0; t2 < 8; t2++) o[t2] *= fac;

    *reinterpret_cast<short4*>(&Plds[w][ln15 * 32 + g * 4])      = *reinterpret_cast<const short4*>(&pb[0]);
    *reinterpret_cast<short4*>(&Plds[w][ln15 * 32 + 16 + g * 4]) = *reinterpret_cast<const short4*>(&pb[4]);
    __builtin_amdgcn_wave_barrier();
    bf16x8 pf = *reinterpret_cast<const bf16x8*>(&Plds[w][ln15 * 32 + g * 8]);

#pragma unroll
    for (int t2 = 0; t2 < 8; t2++) {
      int d = t2 * 16 + ln15;
      bf16x8 vf = *reinterpret_cast<const bf16x8*>(&Vl[buf][d * 32 + ((g ^ (ln15 & 3)) << 3)]);
      o[t2] = MFMA_BF16(vf, pf, o[t2]);
    }
    __builtin_amdgcn_wave_barrier();
    buf ^= 1;
  }

  float inv = 1.f / lsum;
#pragma unroll
  for (int t2 = 0; t2 < 8; t2++)
#pragma unroll
    for (int r = 0; r < 4; r++) {
      int d = t2 * 16 + g * 4 + r;
      att[((size_t)(b * S_ + qi)) * (H_ * D_) + h * D_ + d] = __float2bfloat16(o[t2][r] * inv);
    }
}

// ---------------------------------------------------------------- launcher
extern "C" void kernel_launch(void* const* d_in, const int* in_sizes, int n_in,
                              void* d_out, int out_size, void* d_ws, size_t ws_size,
                              hipStream_t stream) {
  const float* hidden = (const float*)d_in[0];
  const int* wpos = (const int*)d_in[1];
  const int* seq = (const int*)d_in[3];
  const float* Wq = (const float*)d_in[4];
  const float* Wk = (const float*)d_in[5];
  const float* Wv = (const float*)d_in[6];
  const float* Wo = (const float*)d_in[7];

  char* ws = (char*)d_ws;
  bf16* Xb   = (bf16*)(ws);
  bf16* Wqkv = (bf16*)(ws + 16777216);
  bf16* Wob  = (bf16*)(ws + 29360128);
  bf16* QKVb = (bf16*)(ws + 37748736);
  bf16* Ksb  = (bf16*)(ws + 62914560);
  bf16* Vtb  = (bf16*)(ws + 67108864);
  int*  sst  = (int*)(ws + 71303168);
  bf16* Qsb  = Xb;
  bf16* attb = QKVb;

  cvt_f32_bf16<<<dim3(8192), dim3(256), 0, stream>>>(hidden, Xb, 8388608);
  cvt_weights<<<dim3(10240), dim3(256), 0, stream>>>(Wq, Wk, Wv, Wo, Wqkv, Wob);
  seq_start<<<dim3(32), dim3(256), 0, stream>>>(seq, sst);

  // QKV projection: [4096,2048] x [3072,2048]^T -> bf16 [4096,3072]; grid 16x16=256
  gemm8p<256, 192, 1><<<dim3(256), dim3(512), 0, stream>>>(Xb, Wqkv, (void*)QKVb, 4096, 3072, 2048);

  qkv_post<<<dim3(4096), dim3(256), 0, stream>>>(QKVb, wpos, Qsb, Ksb, Vtb);

  attn_fwd<<<dim3(1024), dim3(256), 0, stream>>>(Qsb, Ksb, Vtb, sst, attb);

  // O projection: [4096,2048] x [2048,2048]^T -> fp32 d_out; grid 16x16=256
  gemm8p<256, 128, 0><<<dim3(256), dim3(512), 0, stream>>>(attb, Wob, d_out, 4096, 2048, 2048);
}

// Round 8
// 174.698 us; speedup vs baseline: 1.2998x; 1.0261x over previous
//
#include <hip/hip_runtime.h>
#include <hip/hip_bf16.h>

typedef __hip_bfloat16 bf16;
typedef __attribute__((ext_vector_type(8))) short bf16x8;
typedef __attribute__((ext_vector_type(4))) float f32x4;

#define MFMA_BF16(a, b, c) __builtin_amdgcn_mfma_f32_16x16x32_bf16((a), (b), (c), 0, 0, 0)

#define B_   2
#define S_   2048
#define HID_ 2048
#define H_   16
#define HKV_ 4
#define D_   128

#define GLOAD_LDS(gptr, lptr) \
  __builtin_amdgcn_global_load_lds((const __attribute__((address_space(1))) void*)(gptr), \
                                   (__attribute__((address_space(3))) void*)(lptr), 16, 0, 0)

template <int N>
__device__ __forceinline__ void vmw() {
  if constexpr (N == 0)      asm volatile("s_waitcnt vmcnt(0)" ::: "memory");
  else if constexpr (N == 4) asm volatile("s_waitcnt vmcnt(4)" ::: "memory");
  else if constexpr (N == 5) asm volatile("s_waitcnt vmcnt(5)" ::: "memory");
  else                       asm volatile("s_waitcnt vmcnt(6)" ::: "memory");
}

__device__ __forceinline__ void blk_barrier() {
  __builtin_amdgcn_sched_barrier(0);
  __builtin_amdgcn_s_barrier();
  __builtin_amdgcn_sched_barrier(0);
}

// ---------------------------------------------------------------- fp32 -> bf16, all tensors, one launch
__global__ void cvt_all(const float* __restrict__ hidden, const float* __restrict__ Wq,
                        const float* __restrict__ Wk, const float* __restrict__ Wv,
                        const float* __restrict__ Wo,
                        bf16* __restrict__ Xb, bf16* __restrict__ Wqkv, bf16* __restrict__ Wob) {
  long long i4 = (long long)blockIdx.x * 256 + threadIdx.x;  // float4 index
  const float* src; bf16* dst; long long off;
  if (i4 < 2097152)      { src = hidden; dst = Xb;             off = i4; }
  else if (i4 < 3145728) { src = Wq;     dst = Wqkv;           off = i4 - 2097152; }
  else if (i4 < 3407872) { src = Wk;     dst = Wqkv + 4194304; off = i4 - 3145728; }
  else if (i4 < 3670016) { src = Wv;     dst = Wqkv + 5242880; off = i4 - 3407872; }
  else                   { src = Wo;     dst = Wob;            off = i4 - 3670016; }
  float4 v = *reinterpret_cast<const float4*>(src + off * 4);
  alignas(8) bf16 t[4];
  t[0] = __float2bfloat16(v.x);
  t[1] = __float2bfloat16(v.y);
  t[2] = __float2bfloat16(v.z);
  t[3] = __float2bfloat16(v.w);
  *reinterpret_cast<short4*>(dst + off * 4) = *reinterpret_cast<const short4*>(t);
}

// ---------------------------------------------------------------- per-position sequence start
__global__ void seq_start(const int* __restrict__ seq, int* __restrict__ sstart) {
  int t = blockIdx.x * 256 + threadIdx.x;  // 0..8191
  int b = t >> 11, s = t & (S_ - 1);
  const int* sb = seq + b * S_;
  int sid = sb[s];
  int lo = 0, hi = s;
  while (lo < hi) {
    int mid = (lo + hi) >> 1;
    if (sb[mid] < sid) lo = mid + 1; else hi = mid;
  }
  sstart[t] = lo;
}

// ---------------------------------------------------------------- 4-phase pipelined GEMM, 1 vmcnt/tile
// C[M][N] = A[M][K]*B[N][K]^T.  BK=64; A split in two k-halves [2][2][BM*32];
// B one flat [BN][64] tile per dbuf.  8 waves (2M x 4N), per-wave (BM/2) x (BN/4).
// Phases per tile T: P1 (kh0,m0-3 | stage A-kh1(T+1)), P2 (kh0,m4-7),
//                    P3 (kh1,m0-3 | stage A-kh0(T+2)), P4 (kh1,m4-7 | stage B(T+2), vmcnt).
// FIFO at T.P4 (per-wave queue): ... A0(T+1)@(T-1).P3 [2], B(T+1)@(T-1).P4 [NR],
//   A1(T+1)@T.P1 [2]  <- youngest REQUIRED for tile T+1
//   A0(T+2)@T.P3 [2], B(T+2)@T.P4 [NR]  -> vmcnt(NR+2); vmcnt(0) only at T==NT-2.
// Region safety: every stage targets a region whose last reader finished >=1 barrier earlier
// (A[db][0] free after P2, B[db] free after P3, A/B[dn] free since T-1).
// Swizzles (source-pre-swizzled, linear DMA dest, swizzled ds_read):
//   A: 16B-slot' = slot ^ ((row>>1)&3);  B: slot' = slot ^ (row&7).  Both 2-way = free.
template <int BM, int BN, int OUT_BF16>
__global__ __launch_bounds__(512, 2) void gemm8p(const bf16* __restrict__ A,
                                                 const bf16* __restrict__ Bw,
                                                 void* __restrict__ Cout,
                                                 int M, int N, int K) {
  constexpr int MR = BM / 32;       // 8
  constexpr int NR = BN / 64;       // 3 (BN=192) or 2 (BN=128)
  constexpr int LA = BM / 128;      // 2
  constexpr int QD = NR + 2;        // steady-state vmcnt

  __shared__ bf16 As[2][2][BM * 32];   // [dbuf][khalf]
  __shared__ bf16 Bs[2][BN * 64];      // [dbuf], flat full-BK tile

  const int tid  = threadIdx.x;
  const int lane = tid & 63;
  const int w    = tid >> 6;
  const int wr   = w >> 2;          // 0..1
  const int wc   = w & 3;           // 0..3
  const int ln15 = lane & 15, g = lane >> 4;

  // bijective XCD-chunked remap (grids are multiples of 8)
  const int nwg = gridDim.x;
  int bid = blockIdx.x;
  bid = (bid & 7) * (nwg >> 3) + (bid >> 3);
  const int nbn = N / BN;
  const int m0 = (bid / nbn) * BM;
  const int n0 = (bid % nbn) * BN;

  f32x4 acc[MR][NR] = {};

  auto stageA = [&](int db, int kh, int t) {
    int kc = t * 64 + kh * 32;
#pragma unroll
    for (int r = 0; r < LA; r++) {
      int sIdx = r * 512 + tid;
      int row = sIdx >> 2;
      int ss = (sIdx & 3) ^ ((row >> 1) & 3);
      GLOAD_LDS(A + (size_t)(m0 + row) * K + kc + ss * 8, &As[db][kh][(r * 512 + w * 64) * 8]);
    }
  };
  auto stageB = [&](int db, int t) {
#pragma unroll
    for (int r = 0; r < NR; r++) {
      int sIdx = r * 512 + tid;
      int row = sIdx >> 3;
      int cs = (sIdx & 7) ^ (row & 7);
      GLOAD_LDS(Bw + (size_t)(n0 + row) * K + t * 64 + cs * 8, &Bs[db][(size_t)(r * 512 + w * 64) * 8]);
    }
  };

  bf16x8 af[4], bfr[NR];
  auto rdA = [&](int db, int kh, int mb) {
#pragma unroll
    for (int m = 0; m < 4; m++) {
      int row = wr * (BM / 2) + (mb + m) * 16 + ln15;
      af[m] = *reinterpret_cast<const bf16x8*>(&As[db][kh][row * 32 + ((g ^ ((row >> 1) & 3)) << 3)]);
    }
  };
  auto rdB = [&](int db, int kh) {
#pragma unroll
    for (int n = 0; n < NR; n++) {
      int row = wc * (BN / 4) + n * 16 + ln15;
      int sl = ((kh << 2) + g) ^ (row & 7);
      bfr[n] = *reinterpret_cast<const bf16x8*>(&Bs[db][row * 64 + sl * 8]);
    }
  };
  auto MF = [&](int mb) {
    __builtin_amdgcn_s_setprio(1);
#pragma unroll
    for (int m = 0; m < 4; m++)
#pragma unroll
      for (int n = 0; n < NR; n++)
        acc[mb + m][n] = MFMA_BF16(af[m], bfr[n], acc[mb + m][n]);
    __builtin_amdgcn_s_setprio(0);
  };

  const int NT = K >> 6;  // 32

  // prologue: mimic steady-state issue order of tile -1:
  //   A0(0)[2], A1(0)[2], B(0)[NR], A0(1)[2], B(1)[NR]; required = A(0)+B(0)
  stageA(0, 0, 0);
  stageA(0, 1, 0);
  stageB(0, 0);
  stageA(1, 0, 1);
  stageB(1, 1);
  vmw<QD>();
  blk_barrier();

  for (int T = 0; T < NT; ++T) {
    const int db = T & 1, dn = db ^ 1;

    // P1: kh0, m0-3 | stage A-kh1(T+1)
    rdA(db, 0, 0); rdB(db, 0);
    if (T + 1 < NT) stageA(dn, 1, T + 1);
    blk_barrier(); MF(0); blk_barrier();
    // P2: kh0, m4-7
    rdA(db, 0, 4);
    blk_barrier(); MF(4); blk_barrier();
    // P3: kh1, m0-3 | stage A-kh0(T+2)
    rdA(db, 1, 0); rdB(db, 1);
    if (T + 2 < NT) stageA(db, 0, T + 2);
    blk_barrier(); MF(0); blk_barrier();
    // P4: kh1, m4-7 | stage B(T+2), single checkpoint
    rdA(db, 1, 4);
    if (T + 2 < NT) stageB(db, T + 2);
    if (T + 1 < NT) {
      if (T == NT - 2) vmw<0>(); else vmw<QD>();
    }
    blk_barrier(); MF(4); blk_barrier();
  }

  // epilogue: row = m0 + wr*(BM/2) + m*16 + g*4 + r ; col = n0 + wc*(BN/4) + n*16 + ln15
#pragma unroll
  for (int m = 0; m < MR; m++)
#pragma unroll
    for (int n = 0; n < NR; n++)
#pragma unroll
      for (int r = 0; r < 4; r++) {
        int row = m0 + wr * (BM / 2) + m * 16 + g * 4 + r;
        int col = n0 + wc * (BN / 4) + n * 16 + ln15;
        if constexpr (OUT_BF16) {
          ((bf16*)Cout)[(size_t)row * N + col] = __float2bfloat16(acc[m][n][r]);
        } else {
          ((float*)Cout)[(size_t)row * N + col] = acc[m][n][r];
        }
      }
}

// ---------------------------------------------------------------- clip + RoPE + layout
__global__ __launch_bounds__(256) void qkv_post(const bf16* __restrict__ QKV,
                                                const int* __restrict__ wpos,
                                                bf16* __restrict__ Qs,   // [B][H][S][D]
                                                bf16* __restrict__ Ks,   // [B][HKV][S][D]
                                                bf16* __restrict__ Vt) { // [B][HKV][D][S]
  const int row = blockIdx.x;  // b*S + s
  const int b = row >> 11, s = row & (S_ - 1);
  const int t = threadIdx.x;
  const bf16* R = QKV + (size_t)row * 3072;
  const float pos = (float)wpos[row];
  const float kln = 0.14391156831212787f;   // ln(10000)/64
  const float qscale = 0.08838834764831845f; // 1/sqrt(128)

  for (int p = t; p < 1024; p += 256) {
    int h = p >> 6, i = p & 63;
    float ang = pos * expf(-(float)i * kln);
    float sn, cs;
    sincosf(ang, &sn, &cs);
    float x1 = __bfloat162float(R[h * 128 + i]);
    float x2 = __bfloat162float(R[h * 128 + 64 + i]);
    x1 = fminf(fmaxf(x1, -8.f), 8.f);
    x2 = fminf(fmaxf(x2, -8.f), 8.f);
    float y1 = (x1 * cs - x2 * sn) * qscale;
    float y2 = (x2 * cs + x1 * sn) * qscale;
    size_t qb = ((size_t)(b * H_ + h) * S_ + s) * D_;
    Qs[qb + i]      = __float2bfloat16(y1);
    Qs[qb + 64 + i] = __float2bfloat16(y2);
  }
  {
    int kh = t >> 6, i = t & 63;
    float ang = pos * expf(-(float)i * kln);
    float sn, cs;
    sincosf(ang, &sn, &cs);
    float x1 = __bfloat162float(R[2048 + kh * 128 + i]);
    float x2 = __bfloat162float(R[2048 + kh * 128 + 64 + i]);
    x1 = fminf(fmaxf(x1, -8.f), 8.f);
    x2 = fminf(fmaxf(x2, -8.f), 8.f);
    float y1 = x1 * cs - x2 * sn;
    float y2 = x2 * cs + x1 * sn;
    size_t kb = ((size_t)(b * HKV_ + kh) * S_ + s) * D_;
    Ks[kb + i]      = __float2bfloat16(y1);
    Ks[kb + 64 + i] = __float2bfloat16(y2);
  }
  for (int e = t; e < 512; e += 256) {
    int kh = e >> 7, d = e & 127;
    float x = __bfloat162float(R[2560 + e]);
    x = fminf(fmaxf(x, -8.f), 8.f);
    Vt[((size_t)(b * HKV_ + kh) * D_ + d) * S_ + s] = __float2bfloat16(x);
  }
}

// ---------------------------------------------------------------- flash attention
// Block = 4 waves = the 4 heads of one KV group, same (b, 16-query tile).
__global__ __launch_bounds__(256) void attn_fwd(const bf16* __restrict__ Qs,
                                                const bf16* __restrict__ Ks,
                                                const bf16* __restrict__ Vt,
                                                const int* __restrict__ sstart,
                                                bf16* __restrict__ att) {  // [B][S][H*D]
  __shared__ bf16 Kl[2][32 * 128];
  __shared__ bf16 Vl[2][128 * 32];
  __shared__ bf16 Plds[4][16 * 32];

  const int tid = threadIdx.x;
  const int lane = tid & 63, w = tid >> 6;
  const int ln15 = lane & 15, g = lane >> 4;

  const int wg = ((blockIdx.x & 7) << 7) | (blockIdx.x >> 3);
  const int qt  = wg & 127;
  const int kvh = (wg >> 7) & 3;
  const int b   = wg >> 9;
  const int h   = kvh * 4 + w;
  const int q0  = qt * 16;
  const int qi  = q0 + ln15;

  const bf16* Qrow = Qs + ((size_t)(b * H_ + h) * S_ + qi) * D_;
  bf16x8 qf[4];
#pragma unroll
  for (int c = 0; c < 4; c++)
    qf[c] = *reinterpret_cast<const bf16x8*>(Qrow + c * 32 + g * 8);

  const int sQ = sstart[b * S_ + qi];
  const int kstart = __builtin_amdgcn_readfirstlane(__shfl(sQ, 0));
  const int kend = q0 + 15;

  const bf16* Kb = Ks + (size_t)(b * HKV_ + kvh) * S_ * D_;
  const bf16* Vb = Vt + (size_t)(b * HKV_ + kvh) * D_ * S_;

  auto stage = [&](int buf, int kb) {
#pragma unroll
    for (int p = 0; p < 2; p++) {
      int slot = p * 256 + tid;
      int row = slot >> 4;
      int cs = (slot & 15) ^ (row & 15);
      int gr = min(kb + row, S_ - 1);
      GLOAD_LDS(Kb + (size_t)gr * D_ + cs * 8, &Kl[buf][(p * 256 + w * 64) * 8]);
    }
#pragma unroll
    for (int p = 0; p < 2; p++) {
      int slot = p * 256 + tid;
      int d = slot >> 2, c = slot & 3;
      int cs = c ^ (d & 3);
      int gcol = min(kb + cs * 8, S_ - 8);
      GLOAD_LDS(Vb + (size_t)d * S_ + gcol, &Vl[buf][(p * 256 + w * 64) * 8]);
    }
  };

  float m = -1e30f, lsum = 0.f;
  f32x4 o[8] = {};

  stage(0, kstart);
  int buf = 0;
  for (int kb = kstart; kb <= kend; kb += 32) {
    __syncthreads();
    if (kb + 32 <= kend) stage(buf ^ 1, kb + 32);

    bf16x8 kf0[4], kf1[4];
#pragma unroll
    for (int c = 0; c < 4; c++) {
      kf0[c] = *reinterpret_cast<const bf16x8*>(&Kl[buf][ln15 * 128 + (((c * 4 + g) ^ ln15) << 3)]);
      kf1[c] = *reinterpret_cast<const bf16x8*>(&Kl[buf][(16 + ln15) * 128 + (((c * 4 + g) ^ ln15) << 3)]);
    }
    f32x4 s0 = {0.f, 0.f, 0.f, 0.f}, s1 = {0.f, 0.f, 0.f, 0.f};
#pragma unroll
    for (int c = 0; c < 4; c++) {
      s0 = MFMA_BF16(kf0[c], qf[c], s0);
      s1 = MFMA_BF16(kf1[c], qf[c], s1);
    }

    float sc[8];
    float tmax = -1e30f;
#pragma unroll
    for (int r = 0; r < 4; r++) {
      int k0i = kb + g * 4 + r;
      int k1i = k0i + 16;
      float x0 = (k0i >= sQ && k0i <= qi) ? s0[r] : -1e30f;
      float x1 = (k1i >= sQ && k1i <= qi) ? s1[r] : -1e30f;
      sc[r] = x0;
      sc[4 + r] = x1;
      tmax = fmaxf(tmax, fmaxf(x0, x1));
    }
    tmax = fmaxf(tmax, __shfl_xor(tmax, 16));
    tmax = fmaxf(tmax, __shfl_xor(tmax, 32));
    float mn  = fmaxf(m, tmax);
    float fac = __expf(m - mn);
    float ps = 0.f;
    alignas(16) bf16 pb[8];
#pragma unroll
    for (int i2 = 0; i2 < 8; i2++) {
      float p = (sc[i2] < -1e29f) ? 0.f : __expf(sc[i2] - mn);
      ps += p;
      pb[i2] = __float2bfloat16(p);
    }
    ps += __shfl_xor(ps, 16);
    ps += __shfl_xor(ps, 32);
    lsum = lsum * fac + ps;
    m = mn;
#pragma unroll
    for (int t2 = 0; t2 < 8; t2++) o[t2] *= fac;

    *reinterpret_cast<short4*>(&Plds[w][ln15 * 32 + g * 4])      = *reinterpret_cast<const short4*>(&pb[0]);
    *reinterpret_cast<short4*>(&Plds[w][ln15 * 32 + 16 + g * 4]) = *reinterpret_cast<const short4*>(&pb[4]);
    __builtin_amdgcn_wave_barrier();
    bf16x8 pf = *reinterpret_cast<const bf16x8*>(&Plds[w][ln15 * 32 + g * 8]);

#pragma unroll
    for (int t2 = 0; t2 < 8; t2++) {
      int d = t2 * 16 + ln15;
      bf16x8 vf = *reinterpret_cast<const bf16x8*>(&Vl[buf][d * 32 + ((g ^ (ln15 & 3)) << 3)]);
      o[t2] = MFMA_BF16(vf, pf, o[t2]);
    }
    __builtin_amdgcn_wave_barrier();
    buf ^= 1;
  }

  float inv = 1.f / lsum;
#pragma unroll
  for (int t2 = 0; t2 < 8; t2++)
#pragma unroll
    for (int r = 0; r < 4; r++) {
      int d = t2 * 16 + g * 4 + r;
      att[((size_t)(b * S_ + qi)) * (H_ * D_) + h * D_ + d] = __float2bfloat16(o[t2][r] * inv);
    }
}

// ---------------------------------------------------------------- launcher
extern "C" void kernel_launch(void* const* d_in, const int* in_sizes, int n_in,
                              void* d_out, int out_size, void* d_ws, size_t ws_size,
                              hipStream_t stream) {
  const float* hidden = (const float*)d_in[0];
  const int* wpos = (const int*)d_in[1];
  const int* seq = (const int*)d_in[3];
  const float* Wq = (const float*)d_in[4];
  const float* Wk = (const float*)d_in[5];
  const float* Wv = (const float*)d_in[6];
  const float* Wo = (const float*)d_in[7];

  char* ws = (char*)d_ws;
  bf16* Xb   = (bf16*)(ws);
  bf16* Wqkv = (bf16*)(ws + 16777216);
  bf16* Wob  = (bf16*)(ws + 29360128);
  bf16* QKVb = (bf16*)(ws + 37748736);
  bf16* Ksb  = (bf16*)(ws + 62914560);
  bf16* Vtb  = (bf16*)(ws + 67108864);
  int*  sst  = (int*)(ws + 71303168);
  bf16* Qsb  = Xb;
  bf16* attb = QKVb;

  cvt_all<<<dim3(18432), dim3(256), 0, stream>>>(hidden, Wq, Wk, Wv, Wo, Xb, Wqkv, Wob);
  seq_start<<<dim3(32), dim3(256), 0, stream>>>(seq, sst);

  // QKV projection: [4096,2048] x [3072,2048]^T -> bf16 [4096,3072]; grid 16x16=256
  gemm8p<256, 192, 1><<<dim3(256), dim3(512), 0, stream>>>(Xb, Wqkv, (void*)QKVb, 4096, 3072, 2048);

  qkv_post<<<dim3(4096), dim3(256), 0, stream>>>(QKVb, wpos, Qsb, Ksb, Vtb);

  attn_fwd<<<dim3(1024), dim3(256), 0, stream>>>(Qsb, Ksb, Vtb, sst, attb);

  // O projection: [4096,2048] x [2048,2048]^T -> fp32 d_out; grid 16x16=256
  gemm8p<256, 128, 0><<<dim3(256), dim3(512), 0, stream>>>(attb, Wob, d_out, 4096, 2048, 2048);
}